// Round 6
// baseline (707.944 us; speedup 1.0000x reference)
//
#include <hip/hip_runtime.h>

// Problem constants (from reference)
#define N_C 50000
#define N_V 100000
#define N_A 5000
#define E_C2V 1600000
#define E_A2V 1000000
#define D_V 13
#define D_C 14
#define D_A 14
#define EMB 32

// ---- round 14 (r25): 8-wave blocks + xs prefetch ----
// r24 post-mortem: occupancy pinned at ~8 waves/CU (~2 blocks/CU) across
// r22-r24 regardless of LDS; VALU-seconds conserved -> concurrency-limited.
// This round: k_bin_v uses 512-thread blocks (8 waves stripe the bin) to
// double waves/CU if the cap is per-block, and the xs_b gather is prefetched
// one round ahead (removes ~400cy L2 gather from the per-round chain).
#define CHK 4096
#define NCHG ((E_C2V + CHK - 1) / CHK)  // 391
#define NCHA ((E_A2V + CHK - 1) / CHK)  // 245
#define BINV 64
#define NBINV ((N_V + BINV - 1) / BINV)  // 1563 (last bin 32 nodes)
#define BINA 4
#define NBINA (N_A / BINA)  // 1250 exact
#define CAPG 1280  // mean 1024, sd 32 -> +8 sigma
#define CAPH 848   // mean 640,  sd 25 -> +8.3 sigma
#define CAPA 1040  // mean 800,  sd 28 -> +8.5 sigma
#define CURSTR 8   // pad cursors to one per 32B sector
#define CUR_TOT ((2 * NBINV + NBINA) * CURSTR)  // 35008 ints
#define CUR_BYTES (CUR_TOT * 4)                 // 140032 (64-aligned)

typedef float v2f __attribute__((ext_vector_type(2)));
typedef float f32x4 __attribute__((ext_vector_type(4)));
typedef short bf16x8 __attribute__((ext_vector_type(8)));
typedef unsigned long long u64;

// Pack (key_hi:17b, key_lo:16b, ea as bf16 RNE) into one u64.
__device__ __forceinline__ u64 pack_edge(int hi, int lo, float ea) {
  unsigned b = __float_as_uint(ea);
  b += 0x7FFFu + ((b >> 16) & 1u);  // round-to-nearest-even to bf16
  return ((u64)(unsigned)hi << 32) | ((u64)(unsigned)(lo & 0xFFFF) << 16) |
         (u64)(b >> 16);
}

__device__ __forceinline__ unsigned short bf16r(float x) {
  unsigned u = __float_as_uint(x);
  u += 0x7FFFu + ((u >> 16) & 1u);
  return (unsigned short)(u >> 16);
}

// Pack two floats to bf16 pair (RNE) in one uint: low=a, high=b.
__device__ __forceinline__ unsigned bf16pk(float a, float b) {
  unsigned ua = __float_as_uint(a);
  ua += 0x7FFFu + ((ua >> 16) & 1u);
  unsigned ub = __float_as_uint(b);
  ub += 0x7FFFu + ((ub >> 16) & 1u);
  return (ua >> 16) | (ub & 0xFFFF0000u);
}

// h2[j] (16 x float2 = 32 channels) += v * Wrow[2j..2j+1] via v_pk_fma_f32.
__device__ __forceinline__ void accrow2(v2f* __restrict__ h, float v,
                                        const float* __restrict__ Wrow) {
  const v2f* w = (const v2f*)Wrow;
  v2f vv = {v, v};
#pragma unroll
  for (int j = 0; j < 16; ++j) h[j] = __builtin_elementwise_fma(vv, w[j], h[j]);
}

__device__ __forceinline__ void relu2(v2f* __restrict__ h) {
  v2f z = {0.0f, 0.0f};
#pragma unroll
  for (int j = 0; j < 16; ++j) h[j] = __builtin_elementwise_max(h[j], z);
}

__device__ __forceinline__ void layer2(v2f* __restrict__ o2,
                                       const v2f* __restrict__ h,
                                       const float* __restrict__ W2,
                                       const float* __restrict__ b2) {
  const v2f* b = (const v2f*)b2;
#pragma unroll
  for (int j = 0; j < 16; ++j) o2[j] = b[j];
#pragma unroll
  for (int k = 0; k < EMB; ++k) {
    float hk = h[k >> 1][k & 1];
    accrow2(o2, hk, W2 + k * EMB);
  }
}

// -------- pack x_c / x_a rows to bf16[16] (32B rows, pad zero) --------
__global__ __launch_bounds__(256) void k_pad(
    const float* __restrict__ x_c, const float* __restrict__ x_a,
    unsigned* __restrict__ xc_b, unsigned* __restrict__ xa_b) {
  int i = blockIdx.x * 256 + threadIdx.x;
  if (i < N_C * 8) {
    int r = i >> 3, j = i & 7;
    xc_b[i] = (j < 7) ? bf16pk(x_c[r * D_C + 2 * j], x_c[r * D_C + 2 * j + 1])
                      : 0u;
  } else if (i < (N_C + N_A) * 8) {
    int k = i - N_C * 8;
    int r = k >> 3, j = k & 7;
    xa_b[k] = (j < 7) ? bf16pk(x_a[r * D_A + 2 * j], x_a[r * D_A + 2 * j + 1])
                      : 0u;
  }
}

// ======================= phase 1: fused count + fill =======================

__device__ __forceinline__ void bin_fill_g_body(
    int bid, int tid, const int* __restrict__ c2v_t,
    const int* __restrict__ c2v_s, const float* __restrict__ ea,
    int* __restrict__ gcur, u64* __restrict__ pay_g,
    unsigned* __restrict__ hist) {
  int e0 = bid * CHK;
  int n = E_C2V - e0;
  if (n > CHK) n = CHK;
  for (int i = tid; i < NBINV; i += 256) hist[i] = 0u;
  __syncthreads();
  const int4* t4 = (const int4*)(c2v_t + e0);
  for (int i = tid; i < (n >> 2); i += 256) {
    int4 v = t4[i];
    atomicAdd(&hist[v.x >> 6], 1u);
    atomicAdd(&hist[v.y >> 6], 1u);
    atomicAdd(&hist[v.z >> 6], 1u);
    atomicAdd(&hist[v.w >> 6], 1u);
  }
  __syncthreads();
  int rot = (bid * 131) % NBINV;
  for (int i = tid; i < NBINV; i += 256) {
    int ii = i + rot;
    if (ii >= NBINV) ii -= NBINV;
    unsigned c = hist[ii];
    hist[ii] =
        c ? (unsigned)(ii * CAPG + atomicAdd(&gcur[ii * CURSTR], (int)c)) : 0u;
  }
  __syncthreads();
  for (int i = tid; i < n; i += 256) {
    int e = e0 + i;
    int t = c2v_t[e];
    unsigned pos = atomicAdd(&hist[t >> 6], 1u);
    if (pos < (unsigned)(((t >> 6) + 1) * CAPG))  // 8-sigma overflow guard
      pay_g[pos] = pack_edge(t, c2v_s[e], ea[e]);
  }
}

__device__ __forceinline__ void bin_fill_ha_body(
    int bid, int tid, const int* __restrict__ a2v_t,
    const int* __restrict__ a2v_s, const float* __restrict__ ea,
    int* __restrict__ hcur, int* __restrict__ acur, u64* __restrict__ pay_h,
    u64* __restrict__ pay_a, unsigned* __restrict__ hist) {
  const int nb = NBINV + NBINA;
  int e0 = bid * CHK;
  int n = E_A2V - e0;
  if (n > CHK) n = CHK;
  for (int i = tid; i < nb; i += 256) hist[i] = 0u;
  __syncthreads();
  const int4* t4 = (const int4*)(a2v_t + e0);
  const int4* a4 = (const int4*)(a2v_s + e0);
  for (int i = tid; i < (n >> 2); i += 256) {
    int4 tv = t4[i];
    int4 av = a4[i];
    atomicAdd(&hist[tv.x >> 6], 1u);
    atomicAdd(&hist[tv.y >> 6], 1u);
    atomicAdd(&hist[tv.z >> 6], 1u);
    atomicAdd(&hist[tv.w >> 6], 1u);
    atomicAdd(&hist[NBINV + (av.x >> 2)], 1u);
    atomicAdd(&hist[NBINV + (av.y >> 2)], 1u);
    atomicAdd(&hist[NBINV + (av.z >> 2)], 1u);
    atomicAdd(&hist[NBINV + (av.w >> 2)], 1u);
  }
  __syncthreads();
  int rot = (bid * 131) % nb;
  for (int i = tid; i < nb; i += 256) {
    int ii = i + rot;
    if (ii >= nb) ii -= nb;
    unsigned c = hist[ii];
    unsigned base = 0u;
    if (c) {
      if (ii < NBINV)
        base = (unsigned)(ii * CAPH + atomicAdd(&hcur[ii * CURSTR], (int)c));
      else
        base = (unsigned)((ii - NBINV) * CAPA +
                          atomicAdd(&acur[(ii - NBINV) * CURSTR], (int)c));
    }
    hist[ii] = base;
  }
  __syncthreads();
  for (int i = tid; i < n; i += 256) {
    int e = e0 + i;
    int t = a2v_t[e];
    int a = a2v_s[e];
    u64 pk = pack_edge(t, a, ea[e]);
    unsigned ph = atomicAdd(&hist[t >> 6], 1u);
    if (ph < (unsigned)(((t >> 6) + 1) * CAPH)) pay_h[ph] = pk;
    unsigned pa = atomicAdd(&hist[NBINV + (a >> 2)], 1u);
    if (pa < (unsigned)(((a >> 2) + 1) * CAPA)) pay_a[pa] = pk;
  }
}

__global__ __launch_bounds__(256) void k_bin_fill_all(
    const int* __restrict__ c2v_t, const int* __restrict__ c2v_s,
    const float* __restrict__ ea_g, const int* __restrict__ a2v_t,
    const int* __restrict__ a2v_s, const float* __restrict__ ea_ha,
    int* __restrict__ gcur, int* __restrict__ hcur, int* __restrict__ acur,
    u64* __restrict__ pay_g, u64* __restrict__ pay_h,
    u64* __restrict__ pay_a) {
  __shared__ unsigned hist[NBINV + NBINA];
  if (blockIdx.x < NCHG)
    bin_fill_g_body(blockIdx.x, threadIdx.x, c2v_t, c2v_s, ea_g, gcur, pay_g,
                    hist);
  else
    bin_fill_ha_body(blockIdx.x - NCHG, threadIdx.x, a2v_t, a2v_s, ea_ha, hcur,
                     acur, pay_h, pay_a, hist);
}

__global__ __launch_bounds__(256) void k_bin_fill_g(
    const int* __restrict__ c2v_t, const int* __restrict__ c2v_s,
    const float* __restrict__ ea_g, int* __restrict__ gcur,
    u64* __restrict__ pay_g) {
  __shared__ unsigned hist[NBINV + NBINA];
  bin_fill_g_body(blockIdx.x, threadIdx.x, c2v_t, c2v_s, ea_g, gcur, pay_g,
                  hist);
}

__global__ __launch_bounds__(256) void k_bin_fill_ha(
    const int* __restrict__ a2v_t, const int* __restrict__ a2v_s,
    const float* __restrict__ ea_ha, int* __restrict__ hcur,
    int* __restrict__ acur, u64* __restrict__ pay_h, u64* __restrict__ pay_a) {
  __shared__ unsigned hist[NBINV + NBINA];
  bin_fill_ha_body(blockIdx.x, threadIdx.x, a2v_t, a2v_s, ea_ha, hcur, acur,
                   pay_h, pay_a, hist);
}

// ======== phase 3: per-bin all-MFMA edge MLP + one-hot reduction ========
// 8 waves stripe the bin's payload (512-thread blocks). Per wave-round:
// stage 28 bf16 feats -> 8 MFMA L1 -> 8 MFMA L2 (transposed wb) -> 16 MFMA
// one-hot reduce into reg acc. Payload + xs gather prefetched 1 round deep.
#define NWV 8
#define TPB (NWV * 64)

template <int ADDMODE>
__global__ __launch_bounds__(TPB) void k_bin_v(
    const u64* __restrict__ pay, int CAP, int NSRC,
    const int* __restrict__ cur, const float* __restrict__ x_t,
    const unsigned* __restrict__ xs_b,  // bf16-packed [NSRC][8] u32 rows
    const float* __restrict__ W1, const float* __restrict__ b1,
    const float* __restrict__ W2, const float* __restrict__ b2,
    const float* __restrict__ Wp, float* __restrict__ hacc) {
  __shared__ __align__(16) unsigned short vals[NWV][64][36];  // 36864 B
  __shared__ __align__(16) int nidl[NWV][64];
  __shared__ unsigned degl[BINV + 1];
  __shared__ unsigned xtb[BINV][7];  // packed bf16 pairs of x_t + (xt12|0)
  int tid = threadIdx.x;
  int wv = tid >> 6, lane = tid & 63;
  int b = blockIdx.x;
  int ne = cur[b * CURSTR];
  if (ne > CAP) ne = CAP;
  int nn = N_V - b * BINV;
  if (nn > BINV) nn = BINV;
  for (int i = tid; i < BINV + 1; i += TPB) degl[i] = 0u;
  for (int i = tid; i < nn * 7; i += TPB) {
    int node = i / 7, j = i - node * 7;
    const float* xr = x_t + (size_t)(b * BINV + node) * D_V;
    xtb[node][j] =
        (j < 6) ? bf16pk(xr[2 * j], xr[2 * j + 1]) : (unsigned)bf16r(xr[12]);
  }
  __syncthreads();
  int q = lane >> 4, n = lane & 15;
  // W1 fragments (feature order perm: k<13 -> row k; k==13 -> row 27 (ea);
  // 14<=k<28 -> row k-1; k>=28 -> 0)
  bf16x8 bW1[2];
#pragma unroll
  for (int ni = 0; ni < 2; ++ni)
#pragma unroll
    for (int j = 0; j < 8; ++j) {
      int k = q * 8 + j;
      int row = (k < 13) ? k : ((k == 13) ? 27 : k - 1);
      bW1[ni][j] =
          (k < 28) ? (short)bf16r(W1[row * EMB + ni * 16 + n]) : (short)0;
    }
  float bL1_0 = b1[n], bL1_1 = b1[16 + n];
  // W2 fragments
  bf16x8 bW2[2];
#pragma unroll
  for (int ni = 0; ni < 2; ++ni)
#pragma unroll
    for (int j = 0; j < 8; ++j)
      bW2[ni][j] = (short)bf16r(W2[(q * 8 + j) * EMB + ni * 16 + n]);
  float bL2_0 = b2[n], bL2_1 = b2[16 + n];
  const u64* payb = pay + (size_t)b * CAP;
  unsigned short* vw = &vals[wv][0][0];
  int* nw = &nidl[wv][0];
  f32x4 acc[4][2];
#pragma unroll
  for (int mi = 0; mi < 4; ++mi)
#pragma unroll
    for (int ni = 0; ni < 2; ++ni) acc[mi][ni] = (f32x4){0.f, 0.f, 0.f, 0.f};

  // prologue: payload + xs gather for round 0
  int idx0 = wv * 64 + lane;
  u64 p = payb[(idx0 < ne) ? idx0 : 0];
  if (idx0 >= ne) p = ~0ull;
  uint4 xsa = {0u, 0u, 0u, 0u}, xsb2 = {0u, 0u, 0u, 0u};
  {
    int t0 = (int)(p >> 32);
    int s0 = (int)((p >> 16) & 0xFFFFull);
    if ((((unsigned)t0 >> 6) == (unsigned)b) && (t0 < N_V) && (s0 < NSRC)) {
      const uint4* sp = (const uint4*)(xs_b + ((size_t)s0 << 3));
      xsa = sp[0];
      xsb2 = sp[1];
    }
  }

  for (int base = wv * 64; base < ne; base += TPB) {  // waves independent
    int idx = base + lane;
    // prefetch next round's payload + xs gather (1 deep)
    int idxn = idx + TPB;
    u64 pn = payb[(idxn < ne) ? idxn : 0];
    if (idxn >= ne) pn = ~0ull;
    int tn = (int)(pn >> 32);
    int sn = (int)((pn >> 16) & 0xFFFFull);
    bool usen =
        (((unsigned)tn >> 6) == (unsigned)b) && (tn < N_V) && (sn < NSRC);
    uint4 xsan = {0u, 0u, 0u, 0u}, xsbn = {0u, 0u, 0u, 0u};
    if (usen) {
      const uint4* sp = (const uint4*)(xs_b + ((size_t)sn << 3));
      xsan = sp[0];
      xsbn = sp[1];
    }
    // decode + gate current
    int t = (int)(p >> 32);
    unsigned eab = (unsigned)(p & 0xFFFFull);
    bool use = (((unsigned)t >> 6) == (unsigned)b) && (t < N_V) &&
               ((int)((p >> 16) & 0xFFFFull) < NSRC);
    int tl = t & (BINV - 1);
    nw[lane] = use ? tl : BINV;
    unsigned f0, f1, f2, f3, f4, f5, f6;
    if (use) {
      f0 = xtb[tl][0];
      f1 = xtb[tl][1];
      f2 = xtb[tl][2];
      f3 = xtb[tl][3];
      f4 = xtb[tl][4];
      f5 = xtb[tl][5];
      f6 = xtb[tl][6] | (eab << 16);
      atomicAdd(&degl[tl], 1u);
    } else {
      f0 = f1 = f2 = f3 = f4 = f5 = f6 = 0u;
      xsa = (uint4){0u, 0u, 0u, 0u};
      xsb2 = (uint4){0u, 0u, 0u, 0u};
    }
    {  // stage feature row (8x ds_write_b64, 8B aligned)
      unsigned* hm = (unsigned*)vw + lane * 18;
      *(uint2*)(hm + 0) = make_uint2(f0, f1);
      *(uint2*)(hm + 2) = make_uint2(f2, f3);
      *(uint2*)(hm + 4) = make_uint2(f4, f5);
      *(uint2*)(hm + 6) = make_uint2(f6, xsa.x);
      *(uint2*)(hm + 8) = make_uint2(xsa.y, xsa.z);
      *(uint2*)(hm + 10) = make_uint2(xsa.w, xsb2.x);
      *(uint2*)(hm + 12) = make_uint2(xsb2.y, xsb2.z);
      *(uint2*)(hm + 14) = make_uint2(xsb2.w, 0u);
    }
    asm volatile("" ::: "memory");
    // ---- L1: read ALL feature frags, then MFMA + in-place h writeback ----
    union {
      u64 d[2];
      bf16x8 v;
    } af[4];
#pragma unroll
    for (int mi = 0; mi < 4; ++mi) {
      const u64* rp =
          (const u64*)((const char*)vw + (size_t)(mi * 16 + n) * 72 + q * 16);
      af[mi].d[0] = rp[0];
      af[mi].d[1] = rp[1];
    }
    asm volatile("" ::: "memory");
#pragma unroll
    for (int mi = 0; mi < 4; ++mi) {
#pragma unroll
      for (int ni = 0; ni < 2; ++ni) {
        float bb = ni ? bL1_1 : bL1_0;
        f32x4 c = {bb, bb, bb, bb};
        c = __builtin_amdgcn_mfma_f32_16x16x32_bf16(af[mi].v, bW1[ni], c, 0, 0,
                                                    0);
#pragma unroll
        for (int r = 0; r < 4; ++r)
          vw[(size_t)(mi * 16 + q * 4 + r) * 36 + ni * 16 + n] =
              (unsigned short)bf16r(fmaxf(c[r], 0.f));
      }
    }
    asm volatile("" ::: "memory");
    // ---- L2: read h frags, MFMA, transposed [ch][edge] writeback ----
    union {
      u64 d[2];
      bf16x8 v;
    } af2[4];
#pragma unroll
    for (int mi = 0; mi < 4; ++mi) {
      const u64* rp =
          (const u64*)((const char*)vw + (size_t)(mi * 16 + n) * 72 + q * 16);
      af2[mi].d[0] = rp[0];
      af2[mi].d[1] = rp[1];
    }
    asm volatile("" ::: "memory");
#pragma unroll
    for (int mi = 0; mi < 4; ++mi) {
#pragma unroll
      for (int ni = 0; ni < 2; ++ni) {
        float bb = ni ? bL2_1 : bL2_0;
        f32x4 c = {bb, bb, bb, bb};
        c = __builtin_amdgcn_mfma_f32_16x16x32_bf16(af2[mi].v, bW2[ni], c, 0,
                                                    0, 0);
        uint2 pk;
        pk.x = bf16pk(fmaxf(c[0], 0.f), fmaxf(c[1], 0.f));
        pk.y = bf16pk(fmaxf(c[2], 0.f), fmaxf(c[3], 0.f));
        *(uint2*)(vw + (size_t)(ni * 16 + n) * 72 + mi * 16 + q * 4) = pk;
      }
    }
    asm volatile("" ::: "memory");
    // ---- P3: one-hot MFMA reduction into register acc ----
#pragma unroll
    for (int kh = 0; kh < 2; ++kh) {
      int4 na = *(const int4*)(nw + kh * 32 + q * 8);
      int4 nb = *(const int4*)(nw + kh * 32 + q * 8 + 4);
      bf16x8 bf0 = *(const bf16x8*)(vw + n * 72 + kh * 32 + q * 8);
      bf16x8 bf1 = *(const bf16x8*)(vw + (16 + n) * 72 + kh * 32 + q * 8);
#pragma unroll
      for (int mi = 0; mi < 4; ++mi) {
        int mg = mi * 16 + n;
        union {
          unsigned u[4];
          bf16x8 v;
        } oh;
        oh.u[0] =
            ((na.x == mg) ? 0x3F80u : 0u) | ((na.y == mg) ? 0x3F800000u : 0u);
        oh.u[1] =
            ((na.z == mg) ? 0x3F80u : 0u) | ((na.w == mg) ? 0x3F800000u : 0u);
        oh.u[2] =
            ((nb.x == mg) ? 0x3F80u : 0u) | ((nb.y == mg) ? 0x3F800000u : 0u);
        oh.u[3] =
            ((nb.z == mg) ? 0x3F80u : 0u) | ((nb.w == mg) ? 0x3F800000u : 0u);
        acc[mi][0] = __builtin_amdgcn_mfma_f32_16x16x32_bf16(oh.v, bf0,
                                                             acc[mi][0], 0, 0,
                                                             0);
        acc[mi][1] = __builtin_amdgcn_mfma_f32_16x16x32_bf16(oh.v, bf1,
                                                             acc[mi][1], 0, 0,
                                                             0);
      }
    }
    asm volatile("" ::: "memory");
    p = pn;
    xsa = xsan;
    xsb2 = xsbn;
  }
  __syncthreads();
  // merge: accf aliased onto (dead) staging LDS
  float* accf = (float*)&vals[0][0][0];  // 64*32 f32 = 8 KB
  for (int i = tid; i < BINV * EMB; i += TPB) accf[i] = 0.f;
  __syncthreads();
#pragma unroll
  for (int mi = 0; mi < 4; ++mi)
#pragma unroll
    for (int ni = 0; ni < 2; ++ni)
#pragma unroll
      for (int r = 0; r < 4; ++r)
        atomicAdd(&accf[(mi * 16 + q * 4 + r) * EMB + ni * 16 + n],
                  acc[mi][ni][r]);
  __syncthreads();
  // mean + Wp projection + sole-owner writeback
  int j = tid & 31;
  for (int node = tid >> 5; node < nn; node += (TPB / 32)) {
    float inv = 1.f / fmaxf((float)degl[node], 1.f);
    float out = 0.f;
#pragma unroll
    for (int k = 0; k < EMB; ++k)
      out = fmaf(accf[node * EMB + k], Wp[k * EMB + j], out);
    out *= inv;
    float* dst = &hacc[(size_t)(b * BINV + node) * EMB + j];
    if (ADDMODE) out += *dst;
    *dst = out;
  }
}

// a-side g_a MLP (FIN=47) per 4-node bin -> hacc_a (unchanged from r23).
__global__ __launch_bounds__(256) void k_bin_a(
    const u64* __restrict__ pay, const int* __restrict__ cur,
    const float* __restrict__ xa, const float* __restrict__ fv,
    const float* __restrict__ W1, const float* __restrict__ b1,
    const float* __restrict__ W2, const float* __restrict__ b2,
    const float* __restrict__ Wp, float* __restrict__ hacc_a) {
  __shared__ __align__(16) unsigned short vals[4][64][36];
  __shared__ __align__(16) int nidl[4][64];
  __shared__ float accf_a[BINA * EMB];
  __shared__ unsigned degl[BINA + 1];
  __shared__ float xa_l[BINA * D_A];
  int tid = threadIdx.x;
  int wv = tid >> 6, lane = tid & 63;
  int b = blockIdx.x;
  int ne = cur[b * CURSTR];
  if (ne > CAPA) ne = CAPA;
  if (tid < BINA + 1) degl[tid] = 0u;
  if (tid < BINA * EMB) accf_a[tid] = 0.f;
  for (int i = tid; i < BINA * D_A; i += 256)
    xa_l[i] = xa[(size_t)b * (BINA * D_A) + i];
  __syncthreads();
  int q = lane >> 4, n = lane & 15;
  bf16x8 bfr[2];
#pragma unroll
  for (int ni = 0; ni < 2; ++ni)
#pragma unroll
    for (int j = 0; j < 8; ++j)
      bfr[ni][j] = (short)bf16r(W2[(q * 8 + j) * EMB + ni * 16 + n]);
  float bb0 = b2[n], bb1 = b2[16 + n];
  const u64* payb = pay + (size_t)b * CAPA;
  const v2f* b1v = (const v2f*)b1;
  unsigned short* vw = &vals[wv][0][0];
  int* nw = &nidl[wv][0];
  f32x4 acc2[2];
  acc2[0] = (f32x4){0.f, 0.f, 0.f, 0.f};
  acc2[1] = (f32x4){0.f, 0.f, 0.f, 0.f};

  for (int base = wv * 64; base < ne; base += 256) {
    int idx = base + lane;
    bool valid = idx < ne;
    int t = 0, a = 0;
    float eav = 0.f;
    if (valid) {
      u64 p = payb[idx];
      t = (int)(p >> 32);
      a = (int)((p >> 16) & 0xFFFFull);
      eav = __uint_as_float((unsigned)(p & 0xFFFFull) << 16);
    }
    bool use = valid && ((a >> 2) == b) && (t < N_V);
    nw[lane] = use ? (a & (BINA - 1)) : BINA;  // dummy row 4 discarded at merge
    v2f h[16];
    if (use) {
#pragma unroll
      for (int j = 0; j < 16; ++j) h[j] = b1v[j];
      const float* ps = xa_l + (a & (BINA - 1)) * D_A;
#pragma unroll
      for (int i = 0; i < D_A; ++i) accrow2(h, ps[i], W1 + i * EMB);
      const float4* pf = (const float4*)(fv + (size_t)t * EMB);
#pragma unroll
      for (int qq = 0; qq < 8; ++qq) {
        float4 f = pf[qq];
        accrow2(h, f.x, W1 + (D_A + 4 * qq) * EMB);
        accrow2(h, f.y, W1 + (D_A + 4 * qq + 1) * EMB);
        accrow2(h, f.z, W1 + (D_A + 4 * qq + 2) * EMB);
        accrow2(h, f.w, W1 + (D_A + 4 * qq + 3) * EMB);
      }
      accrow2(h, eav, W1 + 46 * EMB);
      relu2(h);
      atomicAdd(&degl[a & (BINA - 1)], 1u);
    } else {
      v2f z = {0.f, 0.f};
#pragma unroll
      for (int j = 0; j < 16; ++j) h[j] = z;
    }
    {
      unsigned* hm = (unsigned*)vw;
#pragma unroll
      for (int j = 0; j < 16; ++j) hm[lane * 18 + j] = bf16pk(h[j].x, h[j].y);
    }
    asm volatile("" ::: "memory");
    union {
      u64 d[2];
      bf16x8 v;
    } afr[4];
#pragma unroll
    for (int mi = 0; mi < 4; ++mi) {
      const u64* rp =
          (const u64*)((const char*)vw + (size_t)(mi * 16 + n) * 72 + q * 16);
      afr[mi].d[0] = rp[0];
      afr[mi].d[1] = rp[1];
    }
#pragma unroll
    for (int mi = 0; mi < 4; ++mi) {
#pragma unroll
      for (int ni = 0; ni < 2; ++ni) {
        f32x4 c = {0.f, 0.f, 0.f, 0.f};
        c = __builtin_amdgcn_mfma_f32_16x16x32_bf16(afr[mi].v, bfr[ni], c, 0,
                                                    0, 0);
        float bb = ni ? bb1 : bb0;
        uint2 pk;
        pk.x = bf16pk(fmaxf(c[0] + bb, 0.f), fmaxf(c[1] + bb, 0.f));
        pk.y = bf16pk(fmaxf(c[2] + bb, 0.f), fmaxf(c[3] + bb, 0.f));
        *(uint2*)(vw + (ni * 16 + n) * 72 + mi * 16 + q * 4) = pk;
      }
    }
    asm volatile("" ::: "memory");
#pragma unroll
    for (int kh = 0; kh < 2; ++kh) {
      int4 na = *(const int4*)(nw + kh * 32 + q * 8);
      int4 nb = *(const int4*)(nw + kh * 32 + q * 8 + 4);
      bf16x8 bf0 = *(const bf16x8*)(vw + n * 72 + kh * 32 + q * 8);
      bf16x8 bf1 = *(const bf16x8*)(vw + (16 + n) * 72 + kh * 32 + q * 8);
      int mg = n;  // single M-tile: nodes 0..3 live in rows 0..3
      union {
        unsigned u[4];
        bf16x8 v;
      } oh;
      oh.u[0] =
          ((na.x == mg) ? 0x3F80u : 0u) | ((na.y == mg) ? 0x3F800000u : 0u);
      oh.u[1] =
          ((na.z == mg) ? 0x3F80u : 0u) | ((na.w == mg) ? 0x3F800000u : 0u);
      oh.u[2] =
          ((nb.x == mg) ? 0x3F80u : 0u) | ((nb.y == mg) ? 0x3F800000u : 0u);
      oh.u[3] =
          ((nb.z == mg) ? 0x3F80u : 0u) | ((nb.w == mg) ? 0x3F800000u : 0u);
      acc2[0] = __builtin_amdgcn_mfma_f32_16x16x32_bf16(oh.v, bf0, acc2[0], 0,
                                                        0, 0);
      acc2[1] = __builtin_amdgcn_mfma_f32_16x16x32_bf16(oh.v, bf1, acc2[1], 0,
                                                        0, 0);
    }
    asm volatile("" ::: "memory");
  }
  __syncthreads();
  if (q == 0) {  // rows 0..3 (node = r); dummy row 4 lives at q=1 -> dropped
#pragma unroll
    for (int ni = 0; ni < 2; ++ni)
#pragma unroll
      for (int r = 0; r < 4; ++r)
        atomicAdd(&accf_a[r * EMB + ni * 16 + n], acc2[ni][r]);
  }
  __syncthreads();
  int node = tid >> 5;
  int j = tid & 31;
  if (node < BINA) {
    float inv = 1.f / fmaxf((float)degl[node], 1.f);
    float out = 0.f;
#pragma unroll
    for (int k = 0; k < EMB; ++k)
      out = fmaf(accf_a[node * EMB + k], Wp[k * EMB + j], out);
    hacc_a[(size_t)(b * BINA + node) * EMB + j] = out * inv;
  }
}

// -------- f_v node MLP, IN-PLACE on hacc --------
__global__ __launch_bounds__(256) void k_node_fv(
    const float* __restrict__ xv_g, float* hf,
    const float* __restrict__ fW1, const float* __restrict__ fb1,
    const float* __restrict__ fW2, const float* __restrict__ fb2) {
  int v = blockIdx.x * blockDim.x + threadIdx.x;
  if (v >= N_V) return;
  v2f* row = (v2f*)(hf + (size_t)v * EMB);
  const v2f* bv = (const v2f*)fb1;
  v2f h[16];
#pragma unroll
  for (int j = 0; j < 16; ++j) h[j] = bv[j] + row[j];
  const float* pv = xv_g + (size_t)v * D_V;
#pragma unroll
  for (int i = 0; i < D_V; ++i) accrow2(h, pv[i], fW1 + i * EMB);
  relu2(h);
  v2f o2[16];
  layer2(o2, h, fW2, fb2);
  v2f z = {0.0f, 0.0f};
#pragma unroll
  for (int j = 0; j < 16; ++j)
    row[j] = __builtin_elementwise_max(o2[j], z);  // relu_out (+idempotent)
}

// -------- f_a node MLP on pre-accumulated hidden -> d_out ------
__global__ __launch_bounds__(256) void k_node_fa(
    const float* __restrict__ xa, const float* __restrict__ hacc_a,
    const float* __restrict__ W1, const float* __restrict__ b1,
    const float* __restrict__ W2, const float* __restrict__ b2,
    float* __restrict__ out) {
  int a = blockIdx.x * blockDim.x + threadIdx.x;
  if (a >= N_A) return;
  const v2f* hr = (const v2f*)(hacc_a + (size_t)a * EMB);
  const v2f* bv = (const v2f*)b1;
  v2f h[16];
#pragma unroll
  for (int j = 0; j < 16; ++j) h[j] = bv[j] + hr[j];
  const float2* pa = (const float2*)(xa + (size_t)a * D_A);
#pragma unroll
  for (int i = 0; i < 7; ++i) {
    float2 w = pa[i];
    accrow2(h, w.x, W1 + (2 * i) * EMB);
    accrow2(h, w.y, W1 + (2 * i + 1) * EMB);
  }
  relu2(h);
  v2f o2[16];
  layer2(o2, h, W2, b2);
  v2f z = {0.0f, 0.0f};
  v2f* dst = (v2f*)(out + (size_t)a * EMB);
#pragma unroll
  for (int j = 0; j < 16; ++j)
    dst[j] = __builtin_elementwise_max(o2[j], z);
}

extern "C" void kernel_launch(void* const* d_in, const int* in_sizes, int n_in,
                              void* d_out, int out_size, void* d_ws,
                              size_t ws_size, hipStream_t stream) {
  const float* x_c = (const float*)d_in[0];
  const float* x_v = (const float*)d_in[1];
  const float* x_a = (const float*)d_in[2];
  const int* c2v_s = (const int*)d_in[3];
  const int* c2v_t = (const int*)d_in[4];
  const int* a2v_s = (const int*)d_in[5];
  const int* a2v_t = (const int*)d_in[6];
  const float* ea_c2v = (const float*)d_in[7];
  const float* ea_a2v = (const float*)d_in[8];
  const float* gv_W1 = (const float*)d_in[9];
  const float* gv_b1 = (const float*)d_in[10];
  const float* gv_W2 = (const float*)d_in[11];
  const float* gv_b2 = (const float*)d_in[12];
  const float* hv_W1 = (const float*)d_in[13];
  const float* hv_b1 = (const float*)d_in[14];
  const float* hv_W2 = (const float*)d_in[15];
  const float* hv_b2 = (const float*)d_in[16];
  const float* fv_W1 = (const float*)d_in[17];
  const float* fv_b1 = (const float*)d_in[18];
  const float* fv_W2 = (const float*)d_in[19];
  const float* fv_b2 = (const float*)d_in[20];
  const float* ga_W1 = (const float*)d_in[21];
  const float* ga_b1 = (const float*)d_in[22];
  const float* ga_W2 = (const float*)d_in[23];
  const float* ga_b2 = (const float*)d_in[24];
  const float* fa_W1 = (const float*)d_in[25];
  const float* fa_b1 = (const float*)d_in[26];
  const float* fa_W2 = (const float*)d_in[27];
  const float* fa_b2 = (const float*)d_in[28];

  // ---- workspace layout ----
  char* w = (char*)d_ws;
  int* cur = (int*)w;  // [0, CUR_BYTES)
  int* gcur = cur;
  int* hcur = gcur + NBINV * CURSTR;
  int* acur = hcur + NBINV * CURSTR;
  size_t off = CUR_BYTES;
  unsigned* xc_b = (unsigned*)(w + off);
  off += (size_t)N_C * 8 * 4;
  unsigned* xa_b = (unsigned*)(w + off);
  off += (size_t)N_A * 8 * 4;
  float* hacc = (float*)(w + off);  // N_V*32 (becomes fv in-place)
  off += (size_t)N_V * EMB * 4;
  float* hacc_a = (float*)(w + off);  // N_A*32
  off += (size_t)N_A * EMB * 4;
  u64* pay = (u64*)(w + off);

  const size_t pay_big =
      ((size_t)NBINV * (CAPG + CAPH) + (size_t)NBINA * CAPA) * 8;
  bool big = ws_size >= off + pay_big;

  u64* pay_g = pay;
  u64* pay_h = big ? (pay + (size_t)NBINV * CAPG) : pay;  // small: reuse g
  u64* pay_a = pay_h + (size_t)NBINV * CAPH;

  // only the cursors need zeroing (hacc/hacc_a are fully written sole-owner)
  hipMemsetAsync(d_ws, 0, (size_t)CUR_BYTES, stream);

  k_pad<<<((N_C + N_A) * 8 + 255) / 256, 256, 0, stream>>>(x_c, x_a, xc_b,
                                                           xa_b);

  if (big) {
    k_bin_fill_all<<<NCHG + NCHA, 256, 0, stream>>>(
        c2v_t, c2v_s, ea_c2v, a2v_t, a2v_s, ea_a2v, gcur, hcur, acur, pay_g,
        pay_h, pay_a);
    k_bin_v<0><<<NBINV, TPB, 0, stream>>>(
        pay_g, CAPG, N_C, gcur, x_v, xc_b, gv_W1, gv_b1, gv_W2, gv_b2,
        fv_W1 + (size_t)D_V * EMB, hacc);
    k_bin_v<1><<<NBINV, TPB, 0, stream>>>(
        pay_h, CAPH, N_A, hcur, x_v, xa_b, hv_W1, hv_b1, hv_W2, hv_b2,
        fv_W1 + (size_t)(D_V + EMB) * EMB, hacc);
  } else {
    // small-ws: pay_g region time-multiplexed with pay_h/pay_a
    k_bin_fill_g<<<NCHG, 256, 0, stream>>>(c2v_t, c2v_s, ea_c2v, gcur, pay_g);
    k_bin_v<0><<<NBINV, TPB, 0, stream>>>(
        pay_g, CAPG, N_C, gcur, x_v, xc_b, gv_W1, gv_b1, gv_W2, gv_b2,
        fv_W1 + (size_t)D_V * EMB, hacc);
    k_bin_fill_ha<<<NCHA, 256, 0, stream>>>(a2v_t, a2v_s, ea_a2v, hcur, acur,
                                            pay_h, pay_a);
    k_bin_v<1><<<NBINV, TPB, 0, stream>>>(
        pay_h, CAPH, N_A, hcur, x_v, xa_b, hv_W1, hv_b1, hv_W2, hv_b2,
        fv_W1 + (size_t)(D_V + EMB) * EMB, hacc);
  }
  // f_v in-place: hacc rows become fv rows
  k_node_fv<<<(N_V + 255) / 256, 256, 0, stream>>>(x_v, hacc, fv_W1, fv_b1,
                                                   fv_W2, fv_b2);
  // a-side g_a MLP + one-hot MFMA reduce -> hacc_a
  k_bin_a<<<NBINA, 256, 0, stream>>>(pay_a, acur, x_a, hacc, ga_W1, ga_b1,
                                     ga_W2, ga_b2,
                                     fa_W1 + (size_t)D_A * EMB, hacc_a);
  // f_a -> out
  k_node_fa<<<(N_A + 255) / 256, 256, 0, stream>>>(
      x_a, hacc_a, fa_W1, fa_b1, fa_W2, fa_b2, (float*)d_out);
}

// Round 7
// 604.669 us; speedup vs baseline: 1.1708x; 1.1708x over previous
//
#include <hip/hip_runtime.h>

// Problem constants (from reference)
#define N_C 50000
#define N_V 100000
#define N_A 5000
#define E_C2V 1600000
#define E_A2V 1000000
#define D_V 13
#define D_C 14
#define D_A 14
#define EMB 32

// ---- round 15 (r26): 2-tile ILP per wave (r24 base) ----
// r25 post-mortem: more waves/block REGRESSED (contention + setup
// amortization); kernel is per-wave latency-chain bound (~8 lgkm drains +
// global gather per round, 2 waves/SIMD can't hide). This round: back to
// 256t/4-wave blocks; each wave processes TWO independent 64-edge tiles per
// iteration with phases interleaved (stage A,B -> read A,B -> L1 A,B -> ...)
// so every LDS drain overlaps the sibling tile's compute. Payload + xs
// gathers prefetched 1 iteration deep. Separate accA/accB register sets.
#define CHK 4096
#define NCHG ((E_C2V + CHK - 1) / CHK)  // 391
#define NCHA ((E_A2V + CHK - 1) / CHK)  // 245
#define BINV 64
#define NBINV ((N_V + BINV - 1) / BINV)  // 1563 (last bin 32 nodes)
#define BINA 4
#define NBINA (N_A / BINA)  // 1250 exact
#define CAPG 1280  // mean 1024, sd 32 -> +8 sigma
#define CAPH 848   // mean 640,  sd 25 -> +8.3 sigma
#define CAPA 1040  // mean 800,  sd 28 -> +8.5 sigma
#define CURSTR 8   // pad cursors to one per 32B sector
#define CUR_TOT ((2 * NBINV + NBINA) * CURSTR)  // 35008 ints
#define CUR_BYTES (CUR_TOT * 4)                 // 140032 (64-aligned)

typedef float v2f __attribute__((ext_vector_type(2)));
typedef float f32x4 __attribute__((ext_vector_type(4)));
typedef short bf16x8 __attribute__((ext_vector_type(8)));
typedef unsigned long long u64;

// Pack (key_hi:17b, key_lo:16b, ea as bf16 RNE) into one u64.
__device__ __forceinline__ u64 pack_edge(int hi, int lo, float ea) {
  unsigned b = __float_as_uint(ea);
  b += 0x7FFFu + ((b >> 16) & 1u);  // round-to-nearest-even to bf16
  return ((u64)(unsigned)hi << 32) | ((u64)(unsigned)(lo & 0xFFFF) << 16) |
         (u64)(b >> 16);
}

__device__ __forceinline__ unsigned short bf16r(float x) {
  unsigned u = __float_as_uint(x);
  u += 0x7FFFu + ((u >> 16) & 1u);
  return (unsigned short)(u >> 16);
}

// Pack two floats to bf16 pair (RNE) in one uint: low=a, high=b.
__device__ __forceinline__ unsigned bf16pk(float a, float b) {
  unsigned ua = __float_as_uint(a);
  ua += 0x7FFFu + ((ua >> 16) & 1u);
  unsigned ub = __float_as_uint(b);
  ub += 0x7FFFu + ((ub >> 16) & 1u);
  return (ua >> 16) | (ub & 0xFFFF0000u);
}

// h2[j] (16 x float2 = 32 channels) += v * Wrow[2j..2j+1] via v_pk_fma_f32.
__device__ __forceinline__ void accrow2(v2f* __restrict__ h, float v,
                                        const float* __restrict__ Wrow) {
  const v2f* w = (const v2f*)Wrow;
  v2f vv = {v, v};
#pragma unroll
  for (int j = 0; j < 16; ++j) h[j] = __builtin_elementwise_fma(vv, w[j], h[j]);
}

__device__ __forceinline__ void relu2(v2f* __restrict__ h) {
  v2f z = {0.0f, 0.0f};
#pragma unroll
  for (int j = 0; j < 16; ++j) h[j] = __builtin_elementwise_max(h[j], z);
}

__device__ __forceinline__ void layer2(v2f* __restrict__ o2,
                                       const v2f* __restrict__ h,
                                       const float* __restrict__ W2,
                                       const float* __restrict__ b2) {
  const v2f* b = (const v2f*)b2;
#pragma unroll
  for (int j = 0; j < 16; ++j) o2[j] = b[j];
#pragma unroll
  for (int k = 0; k < EMB; ++k) {
    float hk = h[k >> 1][k & 1];
    accrow2(o2, hk, W2 + k * EMB);
  }
}

// -------- pack x_c / x_a rows to bf16[16] (32B rows, pad zero) --------
__global__ __launch_bounds__(256) void k_pad(
    const float* __restrict__ x_c, const float* __restrict__ x_a,
    unsigned* __restrict__ xc_b, unsigned* __restrict__ xa_b) {
  int i = blockIdx.x * 256 + threadIdx.x;
  if (i < N_C * 8) {
    int r = i >> 3, j = i & 7;
    xc_b[i] = (j < 7) ? bf16pk(x_c[r * D_C + 2 * j], x_c[r * D_C + 2 * j + 1])
                      : 0u;
  } else if (i < (N_C + N_A) * 8) {
    int k = i - N_C * 8;
    int r = k >> 3, j = k & 7;
    xa_b[k] = (j < 7) ? bf16pk(x_a[r * D_A + 2 * j], x_a[r * D_A + 2 * j + 1])
                      : 0u;
  }
}

// ======================= phase 1: fused count + fill =======================

__device__ __forceinline__ void bin_fill_g_body(
    int bid, int tid, const int* __restrict__ c2v_t,
    const int* __restrict__ c2v_s, const float* __restrict__ ea,
    int* __restrict__ gcur, u64* __restrict__ pay_g,
    unsigned* __restrict__ hist) {
  int e0 = bid * CHK;
  int n = E_C2V - e0;
  if (n > CHK) n = CHK;
  for (int i = tid; i < NBINV; i += 256) hist[i] = 0u;
  __syncthreads();
  const int4* t4 = (const int4*)(c2v_t + e0);
  for (int i = tid; i < (n >> 2); i += 256) {
    int4 v = t4[i];
    atomicAdd(&hist[v.x >> 6], 1u);
    atomicAdd(&hist[v.y >> 6], 1u);
    atomicAdd(&hist[v.z >> 6], 1u);
    atomicAdd(&hist[v.w >> 6], 1u);
  }
  __syncthreads();
  int rot = (bid * 131) % NBINV;
  for (int i = tid; i < NBINV; i += 256) {
    int ii = i + rot;
    if (ii >= NBINV) ii -= NBINV;
    unsigned c = hist[ii];
    hist[ii] =
        c ? (unsigned)(ii * CAPG + atomicAdd(&gcur[ii * CURSTR], (int)c)) : 0u;
  }
  __syncthreads();
  for (int i = tid; i < n; i += 256) {
    int e = e0 + i;
    int t = c2v_t[e];
    unsigned pos = atomicAdd(&hist[t >> 6], 1u);
    if (pos < (unsigned)(((t >> 6) + 1) * CAPG))  // 8-sigma overflow guard
      pay_g[pos] = pack_edge(t, c2v_s[e], ea[e]);
  }
}

__device__ __forceinline__ void bin_fill_ha_body(
    int bid, int tid, const int* __restrict__ a2v_t,
    const int* __restrict__ a2v_s, const float* __restrict__ ea,
    int* __restrict__ hcur, int* __restrict__ acur, u64* __restrict__ pay_h,
    u64* __restrict__ pay_a, unsigned* __restrict__ hist) {
  const int nb = NBINV + NBINA;
  int e0 = bid * CHK;
  int n = E_A2V - e0;
  if (n > CHK) n = CHK;
  for (int i = tid; i < nb; i += 256) hist[i] = 0u;
  __syncthreads();
  const int4* t4 = (const int4*)(a2v_t + e0);
  const int4* a4 = (const int4*)(a2v_s + e0);
  for (int i = tid; i < (n >> 2); i += 256) {
    int4 tv = t4[i];
    int4 av = a4[i];
    atomicAdd(&hist[tv.x >> 6], 1u);
    atomicAdd(&hist[tv.y >> 6], 1u);
    atomicAdd(&hist[tv.z >> 6], 1u);
    atomicAdd(&hist[tv.w >> 6], 1u);
    atomicAdd(&hist[NBINV + (av.x >> 2)], 1u);
    atomicAdd(&hist[NBINV + (av.y >> 2)], 1u);
    atomicAdd(&hist[NBINV + (av.z >> 2)], 1u);
    atomicAdd(&hist[NBINV + (av.w >> 2)], 1u);
  }
  __syncthreads();
  int rot = (bid * 131) % nb;
  for (int i = tid; i < nb; i += 256) {
    int ii = i + rot;
    if (ii >= nb) ii -= nb;
    unsigned c = hist[ii];
    unsigned base = 0u;
    if (c) {
      if (ii < NBINV)
        base = (unsigned)(ii * CAPH + atomicAdd(&hcur[ii * CURSTR], (int)c));
      else
        base = (unsigned)((ii - NBINV) * CAPA +
                          atomicAdd(&acur[(ii - NBINV) * CURSTR], (int)c));
    }
    hist[ii] = base;
  }
  __syncthreads();
  for (int i = tid; i < n; i += 256) {
    int e = e0 + i;
    int t = a2v_t[e];
    int a = a2v_s[e];
    u64 pk = pack_edge(t, a, ea[e]);
    unsigned ph = atomicAdd(&hist[t >> 6], 1u);
    if (ph < (unsigned)(((t >> 6) + 1) * CAPH)) pay_h[ph] = pk;
    unsigned pa = atomicAdd(&hist[NBINV + (a >> 2)], 1u);
    if (pa < (unsigned)(((a >> 2) + 1) * CAPA)) pay_a[pa] = pk;
  }
}

__global__ __launch_bounds__(256) void k_bin_fill_all(
    const int* __restrict__ c2v_t, const int* __restrict__ c2v_s,
    const float* __restrict__ ea_g, const int* __restrict__ a2v_t,
    const int* __restrict__ a2v_s, const float* __restrict__ ea_ha,
    int* __restrict__ gcur, int* __restrict__ hcur, int* __restrict__ acur,
    u64* __restrict__ pay_g, u64* __restrict__ pay_h,
    u64* __restrict__ pay_a) {
  __shared__ unsigned hist[NBINV + NBINA];
  if (blockIdx.x < NCHG)
    bin_fill_g_body(blockIdx.x, threadIdx.x, c2v_t, c2v_s, ea_g, gcur, pay_g,
                    hist);
  else
    bin_fill_ha_body(blockIdx.x - NCHG, threadIdx.x, a2v_t, a2v_s, ea_ha, hcur,
                     acur, pay_h, pay_a, hist);
}

__global__ __launch_bounds__(256) void k_bin_fill_g(
    const int* __restrict__ c2v_t, const int* __restrict__ c2v_s,
    const float* __restrict__ ea_g, int* __restrict__ gcur,
    u64* __restrict__ pay_g) {
  __shared__ unsigned hist[NBINV + NBINA];
  bin_fill_g_body(blockIdx.x, threadIdx.x, c2v_t, c2v_s, ea_g, gcur, pay_g,
                  hist);
}

__global__ __launch_bounds__(256) void k_bin_fill_ha(
    const int* __restrict__ a2v_t, const int* __restrict__ a2v_s,
    const float* __restrict__ ea_ha, int* __restrict__ hcur,
    int* __restrict__ acur, u64* __restrict__ pay_h, u64* __restrict__ pay_a) {
  __shared__ unsigned hist[NBINV + NBINA];
  bin_fill_ha_body(blockIdx.x, threadIdx.x, a2v_t, a2v_s, ea_ha, hcur, acur,
                   pay_h, pay_a, hist);
}

// ======== phase 3: per-bin all-MFMA edge MLP + one-hot reduction ========
// Two independent 64-edge tiles per wave per iteration, phases interleaved.

struct frags {
  bf16x8 v[4];
};

__device__ __forceinline__ frags read_frags(const unsigned short* vw, int q,
                                            int n) {
  frags f;
#pragma unroll
  for (int mi = 0; mi < 4; ++mi) {
    const u64* rp =
        (const u64*)((const char*)vw + (size_t)(mi * 16 + n) * 72 + q * 16);
    union {
      u64 d[2];
      bf16x8 v;
    } u;
    u.d[0] = rp[0];
    u.d[1] = rp[1];
    f.v[mi] = u.v;
  }
  return f;
}

// L1: MFMA (bias in C-init) -> relu -> bf16 h rows in-place [edge][ch].
__device__ __forceinline__ void l1_mfma_wb(const frags& f,
                                           unsigned short* vw,
                                           const bf16x8* bW, float bb0,
                                           float bb1, int q, int n) {
#pragma unroll
  for (int mi = 0; mi < 4; ++mi) {
#pragma unroll
    for (int ni = 0; ni < 2; ++ni) {
      float bb = ni ? bb1 : bb0;
      f32x4 c = {bb, bb, bb, bb};
      c = __builtin_amdgcn_mfma_f32_16x16x32_bf16(f.v[mi], bW[ni], c, 0, 0, 0);
#pragma unroll
      for (int r = 0; r < 4; ++r)
        vw[(size_t)(mi * 16 + q * 4 + r) * 36 + ni * 16 + n] =
            (unsigned short)bf16r(fmaxf(c[r], 0.f));
    }
  }
}

// L2: MFMA -> relu -> bf16 transposed [ch][edge] (u16 pitch 72 overlay).
__device__ __forceinline__ void l2_mfma_wb(const frags& f,
                                           unsigned short* vw,
                                           const bf16x8* bW, float bb0,
                                           float bb1, int q, int n) {
#pragma unroll
  for (int mi = 0; mi < 4; ++mi) {
#pragma unroll
    for (int ni = 0; ni < 2; ++ni) {
      float bb = ni ? bb1 : bb0;
      f32x4 c = {bb, bb, bb, bb};
      c = __builtin_amdgcn_mfma_f32_16x16x32_bf16(f.v[mi], bW[ni], c, 0, 0, 0);
      uint2 pk;
      pk.x = bf16pk(fmaxf(c[0], 0.f), fmaxf(c[1], 0.f));
      pk.y = bf16pk(fmaxf(c[2], 0.f), fmaxf(c[3], 0.f));
      *(uint2*)(vw + (size_t)(ni * 16 + n) * 72 + mi * 16 + q * 4) = pk;
    }
  }
}

// P3: acc[node][ch] += Onehot(nid) @ ValsT (16 MFMA), regs only.
__device__ __forceinline__ void p3_phase(const unsigned short* vw,
                                         const int* nw, f32x4 (*acc)[2], int q,
                                         int n) {
#pragma unroll
  for (int kh = 0; kh < 2; ++kh) {
    int4 na = *(const int4*)(nw + kh * 32 + q * 8);
    int4 nb = *(const int4*)(nw + kh * 32 + q * 8 + 4);
    bf16x8 bf0 = *(const bf16x8*)(vw + n * 72 + kh * 32 + q * 8);
    bf16x8 bf1 = *(const bf16x8*)(vw + (16 + n) * 72 + kh * 32 + q * 8);
#pragma unroll
    for (int mi = 0; mi < 4; ++mi) {
      int mg = mi * 16 + n;
      union {
        unsigned u[4];
        bf16x8 v;
      } oh;
      oh.u[0] =
          ((na.x == mg) ? 0x3F80u : 0u) | ((na.y == mg) ? 0x3F800000u : 0u);
      oh.u[1] =
          ((na.z == mg) ? 0x3F80u : 0u) | ((na.w == mg) ? 0x3F800000u : 0u);
      oh.u[2] =
          ((nb.x == mg) ? 0x3F80u : 0u) | ((nb.y == mg) ? 0x3F800000u : 0u);
      oh.u[3] =
          ((nb.z == mg) ? 0x3F80u : 0u) | ((nb.w == mg) ? 0x3F800000u : 0u);
      acc[mi][0] =
          __builtin_amdgcn_mfma_f32_16x16x32_bf16(oh.v, bf0, acc[mi][0], 0, 0,
                                                  0);
      acc[mi][1] =
          __builtin_amdgcn_mfma_f32_16x16x32_bf16(oh.v, bf1, acc[mi][1], 0, 0,
                                                  0);
    }
  }
}

// gated xs-row gather (zeros when gate fails -> staged zeros stay inert)
__device__ __forceinline__ void pf_xs(u64 p, int b, int NSRC,
                                      const unsigned* __restrict__ xs_b,
                                      uint4& xa, uint4& xb) {
  int t = (int)(p >> 32);
  int s = (int)((p >> 16) & 0xFFFFull);
  if ((((unsigned)t >> 6) == (unsigned)b) && (t < N_V) && (s < NSRC)) {
    const uint4* sp = (const uint4*)(xs_b + ((size_t)s << 3));
    xa = sp[0];
    xb = sp[1];
  } else {
    xa = (uint4){0u, 0u, 0u, 0u};
    xb = (uint4){0u, 0u, 0u, 0u};
  }
}

__device__ __forceinline__ void stage_tile(u64 p, uint4 xsa, uint4 xsb2, int b,
                                           int NSRC, unsigned short* vw,
                                           int* nw, unsigned* degl,
                                           const unsigned (*xtb)[7],
                                           int lane) {
  int t = (int)(p >> 32);
  int s = (int)((p >> 16) & 0xFFFFull);
  unsigned eab = (unsigned)(p & 0xFFFFull);
  bool use = (((unsigned)t >> 6) == (unsigned)b) && (t < N_V) && (s < NSRC);
  int tl = t & (BINV - 1);
  nw[lane] = use ? tl : BINV;
  unsigned f0, f1, f2, f3, f4, f5, f6;
  if (use) {
    f0 = xtb[tl][0];
    f1 = xtb[tl][1];
    f2 = xtb[tl][2];
    f3 = xtb[tl][3];
    f4 = xtb[tl][4];
    f5 = xtb[tl][5];
    f6 = xtb[tl][6] | (eab << 16);
    atomicAdd(&degl[tl], 1u);
  } else {
    f0 = f1 = f2 = f3 = f4 = f5 = f6 = 0u;  // xs already zeroed by pf_xs gate
  }
  unsigned* hm = (unsigned*)vw + lane * 18;
  *(uint2*)(hm + 0) = make_uint2(f0, f1);
  *(uint2*)(hm + 2) = make_uint2(f2, f3);
  *(uint2*)(hm + 4) = make_uint2(f4, f5);
  *(uint2*)(hm + 6) = make_uint2(f6, xsa.x);
  *(uint2*)(hm + 8) = make_uint2(xsa.y, xsa.z);
  *(uint2*)(hm + 10) = make_uint2(xsa.w, xsb2.x);
  *(uint2*)(hm + 12) = make_uint2(xsb2.y, xsb2.z);
  *(uint2*)(hm + 14) = make_uint2(xsb2.w, 0u);
}

template <int ADDMODE>
__global__ __launch_bounds__(256) void k_bin_v(
    const u64* __restrict__ pay, int CAP, int NSRC,
    const int* __restrict__ cur, const float* __restrict__ x_t,
    const unsigned* __restrict__ xs_b,  // bf16-packed [NSRC][8] u32 rows
    const float* __restrict__ W1, const float* __restrict__ b1,
    const float* __restrict__ W2, const float* __restrict__ b2,
    const float* __restrict__ Wp, float* __restrict__ hacc) {
  __shared__ __align__(16) unsigned short vals[4][2][64][36];  // 36864 B
  __shared__ __align__(16) int nidl[4][2][64];
  __shared__ unsigned degl[BINV + 1];
  __shared__ unsigned xtb[BINV][7];  // packed bf16 pairs of x_t + (xt12|0)
  int tid = threadIdx.x;
  int wv = tid >> 6, lane = tid & 63;
  int b = blockIdx.x;
  int ne = cur[b * CURSTR];
  if (ne > CAP) ne = CAP;
  int nn = N_V - b * BINV;
  if (nn > BINV) nn = BINV;
  for (int i = tid; i < BINV + 1; i += 256) degl[i] = 0u;
  for (int i = tid; i < nn * 7; i += 256) {
    int node = i / 7, j = i - node * 7;
    const float* xr = x_t + (size_t)(b * BINV + node) * D_V;
    xtb[node][j] =
        (j < 6) ? bf16pk(xr[2 * j], xr[2 * j + 1]) : (unsigned)bf16r(xr[12]);
  }
  __syncthreads();
  int q = lane >> 4, n = lane & 15;
  // W1 fragments (feature order perm: k<13 -> row k; k==13 -> row 27 (ea);
  // 14<=k<28 -> row k-1; k>=28 -> 0)
  bf16x8 bW1[2];
#pragma unroll
  for (int ni = 0; ni < 2; ++ni)
#pragma unroll
    for (int j = 0; j < 8; ++j) {
      int k = q * 8 + j;
      int row = (k < 13) ? k : ((k == 13) ? 27 : k - 1);
      bW1[ni][j] =
          (k < 28) ? (short)bf16r(W1[row * EMB + ni * 16 + n]) : (short)0;
    }
  float bL1_0 = b1[n], bL1_1 = b1[16 + n];
  bf16x8 bW2[2];
#pragma unroll
  for (int ni = 0; ni < 2; ++ni)
#pragma unroll
    for (int j = 0; j < 8; ++j)
      bW2[ni][j] = (short)bf16r(W2[(q * 8 + j) * EMB + ni * 16 + n]);
  float bL2_0 = b2[n], bL2_1 = b2[16 + n];
  const u64* payb = pay + (size_t)b * CAP;
  unsigned short* vwA = &vals[wv][0][0][0];
  unsigned short* vwB = &vals[wv][1][0][0];
  int* nwA = &nidl[wv][0][0];
  int* nwB = &nidl[wv][1][0];
  f32x4 accA[4][2], accB[4][2];
#pragma unroll
  for (int mi = 0; mi < 4; ++mi)
#pragma unroll
    for (int ni = 0; ni < 2; ++ni) {
      accA[mi][ni] = (f32x4){0.f, 0.f, 0.f, 0.f};
      accB[mi][ni] = (f32x4){0.f, 0.f, 0.f, 0.f};
    }

  int tb = wv * 128;
  // prologue: payload + xs for iteration 0 (both tiles)
  int iA0 = tb + lane, iB0 = tb + 64 + lane;
  u64 pA = payb[(iA0 < ne) ? iA0 : 0];
  if (iA0 >= ne) pA = ~0ull;
  u64 pB = payb[(iB0 < ne) ? iB0 : 0];
  if (iB0 >= ne) pB = ~0ull;
  uint4 xaA, xbA, xaB, xbB;
  pf_xs(pA, b, NSRC, xs_b, xaA, xbA);
  pf_xs(pB, b, NSRC, xs_b, xaB, xbB);

  for (int base = tb; base < ne; base += 512) {
    // prefetch next iteration (payload + xs, both tiles)
    int iAn = base + 512 + lane, iBn = base + 576 + lane;
    u64 pAn = payb[(iAn < ne) ? iAn : 0];
    if (iAn >= ne) pAn = ~0ull;
    u64 pBn = payb[(iBn < ne) ? iBn : 0];
    if (iBn >= ne) pBn = ~0ull;
    uint4 xaAn, xbAn, xaBn, xbBn;
    pf_xs(pAn, b, NSRC, xs_b, xaAn, xbAn);
    pf_xs(pBn, b, NSRC, xs_b, xaBn, xbBn);
    // stage both tiles
    stage_tile(pA, xaA, xbA, b, NSRC, vwA, nwA, degl, xtb, lane);
    stage_tile(pB, xaB, xbB, b, NSRC, vwB, nwB, degl, xtb, lane);
    asm volatile("" ::: "memory");
    // L1 frag reads (both), then MFMA+wb (both)
    frags fA = read_frags(vwA, q, n);
    frags fB = read_frags(vwB, q, n);
    asm volatile("" ::: "memory");
    l1_mfma_wb(fA, vwA, bW1, bL1_0, bL1_1, q, n);
    l1_mfma_wb(fB, vwB, bW1, bL1_0, bL1_1, q, n);
    asm volatile("" ::: "memory");
    frags gA = read_frags(vwA, q, n);
    frags gB = read_frags(vwB, q, n);
    asm volatile("" ::: "memory");
    l2_mfma_wb(gA, vwA, bW2, bL2_0, bL2_1, q, n);
    l2_mfma_wb(gB, vwB, bW2, bL2_0, bL2_1, q, n);
    asm volatile("" ::: "memory");
    p3_phase(vwA, nwA, accA, q, n);
    p3_phase(vwB, nwB, accB, q, n);
    asm volatile("" ::: "memory");
    pA = pAn;
    pB = pBn;
    xaA = xaAn;
    xbA = xbAn;
    xaB = xaBn;
    xbB = xbBn;
  }
  __syncthreads();
  // merge: accf aliased onto (dead) staging LDS
  float* accf = (float*)&vals[0][0][0][0];  // 64*32 f32 = 8 KB
  for (int i = tid; i < BINV * EMB; i += 256) accf[i] = 0.f;
  __syncthreads();
#pragma unroll
  for (int mi = 0; mi < 4; ++mi)
#pragma unroll
    for (int ni = 0; ni < 2; ++ni)
#pragma unroll
      for (int r = 0; r < 4; ++r)
        atomicAdd(&accf[(mi * 16 + q * 4 + r) * EMB + ni * 16 + n],
                  accA[mi][ni][r] + accB[mi][ni][r]);
  __syncthreads();
  // mean + Wp projection + sole-owner writeback
  int j = tid & 31;
  for (int node = tid >> 5; node < nn; node += 8) {
    float inv = 1.f / fmaxf((float)degl[node], 1.f);
    float out = 0.f;
#pragma unroll
    for (int k = 0; k < EMB; ++k)
      out = fmaf(accf[node * EMB + k], Wp[k * EMB + j], out);
    out *= inv;
    float* dst = &hacc[(size_t)(b * BINV + node) * EMB + j];
    if (ADDMODE) out += *dst;
    *dst = out;
  }
}

// a-side g_a MLP (FIN=47) per 4-node bin -> hacc_a (unchanged from r23).
__global__ __launch_bounds__(256) void k_bin_a(
    const u64* __restrict__ pay, const int* __restrict__ cur,
    const float* __restrict__ xa, const float* __restrict__ fv,
    const float* __restrict__ W1, const float* __restrict__ b1,
    const float* __restrict__ W2, const float* __restrict__ b2,
    const float* __restrict__ Wp, float* __restrict__ hacc_a) {
  __shared__ __align__(16) unsigned short vals[4][64][36];
  __shared__ __align__(16) int nidl[4][64];
  __shared__ float accf_a[BINA * EMB];
  __shared__ unsigned degl[BINA + 1];
  __shared__ float xa_l[BINA * D_A];
  int tid = threadIdx.x;
  int wv = tid >> 6, lane = tid & 63;
  int b = blockIdx.x;
  int ne = cur[b * CURSTR];
  if (ne > CAPA) ne = CAPA;
  if (tid < BINA + 1) degl[tid] = 0u;
  if (tid < BINA * EMB) accf_a[tid] = 0.f;
  for (int i = tid; i < BINA * D_A; i += 256)
    xa_l[i] = xa[(size_t)b * (BINA * D_A) + i];
  __syncthreads();
  int q = lane >> 4, n = lane & 15;
  bf16x8 bfr[2];
#pragma unroll
  for (int ni = 0; ni < 2; ++ni)
#pragma unroll
    for (int j = 0; j < 8; ++j)
      bfr[ni][j] = (short)bf16r(W2[(q * 8 + j) * EMB + ni * 16 + n]);
  float bb0 = b2[n], bb1 = b2[16 + n];
  const u64* payb = pay + (size_t)b * CAPA;
  const v2f* b1v = (const v2f*)b1;
  unsigned short* vw = &vals[wv][0][0];
  int* nw = &nidl[wv][0];
  f32x4 acc2[2];
  acc2[0] = (f32x4){0.f, 0.f, 0.f, 0.f};
  acc2[1] = (f32x4){0.f, 0.f, 0.f, 0.f};

  for (int base = wv * 64; base < ne; base += 256) {
    int idx = base + lane;
    bool valid = idx < ne;
    int t = 0, a = 0;
    float eav = 0.f;
    if (valid) {
      u64 p = payb[idx];
      t = (int)(p >> 32);
      a = (int)((p >> 16) & 0xFFFFull);
      eav = __uint_as_float((unsigned)(p & 0xFFFFull) << 16);
    }
    bool use = valid && ((a >> 2) == b) && (t < N_V);
    nw[lane] = use ? (a & (BINA - 1)) : BINA;  // dummy row 4 discarded at merge
    v2f h[16];
    if (use) {
#pragma unroll
      for (int j = 0; j < 16; ++j) h[j] = b1v[j];
      const float* ps = xa_l + (a & (BINA - 1)) * D_A;
#pragma unroll
      for (int i = 0; i < D_A; ++i) accrow2(h, ps[i], W1 + i * EMB);
      const float4* pf = (const float4*)(fv + (size_t)t * EMB);
#pragma unroll
      for (int qq = 0; qq < 8; ++qq) {
        float4 f = pf[qq];
        accrow2(h, f.x, W1 + (D_A + 4 * qq) * EMB);
        accrow2(h, f.y, W1 + (D_A + 4 * qq + 1) * EMB);
        accrow2(h, f.z, W1 + (D_A + 4 * qq + 2) * EMB);
        accrow2(h, f.w, W1 + (D_A + 4 * qq + 3) * EMB);
      }
      accrow2(h, eav, W1 + 46 * EMB);
      relu2(h);
      atomicAdd(&degl[a & (BINA - 1)], 1u);
    } else {
      v2f z = {0.f, 0.f};
#pragma unroll
      for (int j = 0; j < 16; ++j) h[j] = z;
    }
    {
      unsigned* hm = (unsigned*)vw;
#pragma unroll
      for (int j = 0; j < 16; ++j) hm[lane * 18 + j] = bf16pk(h[j].x, h[j].y);
    }
    asm volatile("" ::: "memory");
    union {
      u64 d[2];
      bf16x8 v;
    } afr[4];
#pragma unroll
    for (int mi = 0; mi < 4; ++mi) {
      const u64* rp =
          (const u64*)((const char*)vw + (size_t)(mi * 16 + n) * 72 + q * 16);
      afr[mi].d[0] = rp[0];
      afr[mi].d[1] = rp[1];
    }
#pragma unroll
    for (int mi = 0; mi < 4; ++mi) {
#pragma unroll
      for (int ni = 0; ni < 2; ++ni) {
        f32x4 c = {0.f, 0.f, 0.f, 0.f};
        c = __builtin_amdgcn_mfma_f32_16x16x32_bf16(afr[mi].v, bfr[ni], c, 0,
                                                    0, 0);
        float bb = ni ? bb1 : bb0;
        uint2 pk;
        pk.x = bf16pk(fmaxf(c[0] + bb, 0.f), fmaxf(c[1] + bb, 0.f));
        pk.y = bf16pk(fmaxf(c[2] + bb, 0.f), fmaxf(c[3] + bb, 0.f));
        *(uint2*)(vw + (ni * 16 + n) * 72 + mi * 16 + q * 4) = pk;
      }
    }
    asm volatile("" ::: "memory");
#pragma unroll
    for (int kh = 0; kh < 2; ++kh) {
      int4 na = *(const int4*)(nw + kh * 32 + q * 8);
      int4 nb = *(const int4*)(nw + kh * 32 + q * 8 + 4);
      bf16x8 bf0 = *(const bf16x8*)(vw + n * 72 + kh * 32 + q * 8);
      bf16x8 bf1 = *(const bf16x8*)(vw + (16 + n) * 72 + kh * 32 + q * 8);
      int mg = n;  // single M-tile: nodes 0..3 live in rows 0..3
      union {
        unsigned u[4];
        bf16x8 v;
      } oh;
      oh.u[0] =
          ((na.x == mg) ? 0x3F80u : 0u) | ((na.y == mg) ? 0x3F800000u : 0u);
      oh.u[1] =
          ((na.z == mg) ? 0x3F80u : 0u) | ((na.w == mg) ? 0x3F800000u : 0u);
      oh.u[2] =
          ((nb.x == mg) ? 0x3F80u : 0u) | ((nb.y == mg) ? 0x3F800000u : 0u);
      oh.u[3] =
          ((nb.z == mg) ? 0x3F80u : 0u) | ((nb.w == mg) ? 0x3F800000u : 0u);
      acc2[0] = __builtin_amdgcn_mfma_f32_16x16x32_bf16(oh.v, bf0, acc2[0], 0,
                                                        0, 0);
      acc2[1] = __builtin_amdgcn_mfma_f32_16x16x32_bf16(oh.v, bf1, acc2[1], 0,
                                                        0, 0);
    }
    asm volatile("" ::: "memory");
  }
  __syncthreads();
  if (q == 0) {  // rows 0..3 (node = r); dummy row 4 lives at q=1 -> dropped
#pragma unroll
    for (int ni = 0; ni < 2; ++ni)
#pragma unroll
      for (int r = 0; r < 4; ++r)
        atomicAdd(&accf_a[r * EMB + ni * 16 + n], acc2[ni][r]);
  }
  __syncthreads();
  int node = tid >> 5;
  int j = tid & 31;
  if (node < BINA) {
    float inv = 1.f / fmaxf((float)degl[node], 1.f);
    float out = 0.f;
#pragma unroll
    for (int k = 0; k < EMB; ++k)
      out = fmaf(accf_a[node * EMB + k], Wp[k * EMB + j], out);
    hacc_a[(size_t)(b * BINA + node) * EMB + j] = out * inv;
  }
}

// -------- f_v node MLP, IN-PLACE on hacc --------
__global__ __launch_bounds__(256) void k_node_fv(
    const float* __restrict__ xv_g, float* hf,
    const float* __restrict__ fW1, const float* __restrict__ fb1,
    const float* __restrict__ fW2, const float* __restrict__ fb2) {
  int v = blockIdx.x * blockDim.x + threadIdx.x;
  if (v >= N_V) return;
  v2f* row = (v2f*)(hf + (size_t)v * EMB);
  const v2f* bv = (const v2f*)fb1;
  v2f h[16];
#pragma unroll
  for (int j = 0; j < 16; ++j) h[j] = bv[j] + row[j];
  const float* pv = xv_g + (size_t)v * D_V;
#pragma unroll
  for (int i = 0; i < D_V; ++i) accrow2(h, pv[i], fW1 + i * EMB);
  relu2(h);
  v2f o2[16];
  layer2(o2, h, fW2, fb2);
  v2f z = {0.0f, 0.0f};
#pragma unroll
  for (int j = 0; j < 16; ++j)
    row[j] = __builtin_elementwise_max(o2[j], z);  // relu_out (+idempotent)
}

// -------- f_a node MLP on pre-accumulated hidden -> d_out ------
__global__ __launch_bounds__(256) void k_node_fa(
    const float* __restrict__ xa, const float* __restrict__ hacc_a,
    const float* __restrict__ W1, const float* __restrict__ b1,
    const float* __restrict__ W2, const float* __restrict__ b2,
    float* __restrict__ out) {
  int a = blockIdx.x * blockDim.x + threadIdx.x;
  if (a >= N_A) return;
  const v2f* hr = (const v2f*)(hacc_a + (size_t)a * EMB);
  const v2f* bv = (const v2f*)b1;
  v2f h[16];
#pragma unroll
  for (int j = 0; j < 16; ++j) h[j] = bv[j] + hr[j];
  const float2* pa = (const float2*)(xa + (size_t)a * D_A);
#pragma unroll
  for (int i = 0; i < 7; ++i) {
    float2 w = pa[i];
    accrow2(h, w.x, W1 + (2 * i) * EMB);
    accrow2(h, w.y, W1 + (2 * i + 1) * EMB);
  }
  relu2(h);
  v2f o2[16];
  layer2(o2, h, W2, b2);
  v2f z = {0.0f, 0.0f};
  v2f* dst = (v2f*)(out + (size_t)a * EMB);
#pragma unroll
  for (int j = 0; j < 16; ++j)
    dst[j] = __builtin_elementwise_max(o2[j], z);
}

extern "C" void kernel_launch(void* const* d_in, const int* in_sizes, int n_in,
                              void* d_out, int out_size, void* d_ws,
                              size_t ws_size, hipStream_t stream) {
  const float* x_c = (const float*)d_in[0];
  const float* x_v = (const float*)d_in[1];
  const float* x_a = (const float*)d_in[2];
  const int* c2v_s = (const int*)d_in[3];
  const int* c2v_t = (const int*)d_in[4];
  const int* a2v_s = (const int*)d_in[5];
  const int* a2v_t = (const int*)d_in[6];
  const float* ea_c2v = (const float*)d_in[7];
  const float* ea_a2v = (const float*)d_in[8];
  const float* gv_W1 = (const float*)d_in[9];
  const float* gv_b1 = (const float*)d_in[10];
  const float* gv_W2 = (const float*)d_in[11];
  const float* gv_b2 = (const float*)d_in[12];
  const float* hv_W1 = (const float*)d_in[13];
  const float* hv_b1 = (const float*)d_in[14];
  const float* hv_W2 = (const float*)d_in[15];
  const float* hv_b2 = (const float*)d_in[16];
  const float* fv_W1 = (const float*)d_in[17];
  const float* fv_b1 = (const float*)d_in[18];
  const float* fv_W2 = (const float*)d_in[19];
  const float* fv_b2 = (const float*)d_in[20];
  const float* ga_W1 = (const float*)d_in[21];
  const float* ga_b1 = (const float*)d_in[22];
  const float* ga_W2 = (const float*)d_in[23];
  const float* ga_b2 = (const float*)d_in[24];
  const float* fa_W1 = (const float*)d_in[25];
  const float* fa_b1 = (const float*)d_in[26];
  const float* fa_W2 = (const float*)d_in[27];
  const float* fa_b2 = (const float*)d_in[28];

  // ---- workspace layout ----
  char* w = (char*)d_ws;
  int* cur = (int*)w;  // [0, CUR_BYTES)
  int* gcur = cur;
  int* hcur = gcur + NBINV * CURSTR;
  int* acur = hcur + NBINV * CURSTR;
  size_t off = CUR_BYTES;
  unsigned* xc_b = (unsigned*)(w + off);
  off += (size_t)N_C * 8 * 4;
  unsigned* xa_b = (unsigned*)(w + off);
  off += (size_t)N_A * 8 * 4;
  float* hacc = (float*)(w + off);  // N_V*32 (becomes fv in-place)
  off += (size_t)N_V * EMB * 4;
  float* hacc_a = (float*)(w + off);  // N_A*32
  off += (size_t)N_A * EMB * 4;
  u64* pay = (u64*)(w + off);

  const size_t pay_big =
      ((size_t)NBINV * (CAPG + CAPH) + (size_t)NBINA * CAPA) * 8;
  bool big = ws_size >= off + pay_big;

  u64* pay_g = pay;
  u64* pay_h = big ? (pay + (size_t)NBINV * CAPG) : pay;  // small: reuse g
  u64* pay_a = pay_h + (size_t)NBINV * CAPH;

  // only the cursors need zeroing (hacc/hacc_a are fully written sole-owner)
  hipMemsetAsync(d_ws, 0, (size_t)CUR_BYTES, stream);

  k_pad<<<((N_C + N_A) * 8 + 255) / 256, 256, 0, stream>>>(x_c, x_a, xc_b,
                                                           xa_b);

  if (big) {
    k_bin_fill_all<<<NCHG + NCHA, 256, 0, stream>>>(
        c2v_t, c2v_s, ea_c2v, a2v_t, a2v_s, ea_a2v, gcur, hcur, acur, pay_g,
        pay_h, pay_a);
    k_bin_v<0><<<NBINV, 256, 0, stream>>>(
        pay_g, CAPG, N_C, gcur, x_v, xc_b, gv_W1, gv_b1, gv_W2, gv_b2,
        fv_W1 + (size_t)D_V * EMB, hacc);
    k_bin_v<1><<<NBINV, 256, 0, stream>>>(
        pay_h, CAPH, N_A, hcur, x_v, xa_b, hv_W1, hv_b1, hv_W2, hv_b2,
        fv_W1 + (size_t)(D_V + EMB) * EMB, hacc);
  } else {
    // small-ws: pay_g region time-multiplexed with pay_h/pay_a
    k_bin_fill_g<<<NCHG, 256, 0, stream>>>(c2v_t, c2v_s, ea_c2v, gcur, pay_g);
    k_bin_v<0><<<NBINV, 256, 0, stream>>>(
        pay_g, CAPG, N_C, gcur, x_v, xc_b, gv_W1, gv_b1, gv_W2, gv_b2,
        fv_W1 + (size_t)D_V * EMB, hacc);
    k_bin_fill_ha<<<NCHA, 256, 0, stream>>>(a2v_t, a2v_s, ea_a2v, hcur, acur,
                                            pay_h, pay_a);
    k_bin_v<1><<<NBINV, 256, 0, stream>>>(
        pay_h, CAPH, N_A, hcur, x_v, xa_b, hv_W1, hv_b1, hv_W2, hv_b2,
        fv_W1 + (size_t)(D_V + EMB) * EMB, hacc);
  }
  // f_v in-place: hacc rows become fv rows
  k_node_fv<<<(N_V + 255) / 256, 256, 0, stream>>>(x_v, hacc, fv_W1, fv_b1,
                                                   fv_W2, fv_b2);
  // a-side g_a MLP + one-hot MFMA reduce -> hacc_a
  k_bin_a<<<NBINA, 256, 0, stream>>>(pay_a, acur, x_a, hacc, ga_W1, ga_b1,
                                     ga_W2, ga_b2,
                                     fa_W1 + (size_t)D_A * EMB, hacc_a);
  // f_a -> out
  k_node_fa<<<(N_A + 255) / 256, 256, 0, stream>>>(
      x_a, hacc_a, fa_W1, fa_b1, fa_W2, fa_b2, (float*)d_out);
}

// Round 8
// 510.844 us; speedup vs baseline: 1.3858x; 1.1837x over previous
//
#include <hip/hip_runtime.h>

// Problem constants (from reference)
#define N_C 50000
#define N_V 100000
#define N_A 5000
#define E_C2V 1600000
#define E_A2V 1000000
#define D_V 13
#define D_C 14
#define D_A 14
#define EMB 32

// ---- round 16 (r27): r24 k_bin_v revert + dispatch fusion + CHK=8192 ----
// r25/r26 post-mortem: both TLP (8 waves) and ILP (2 tiles) perturbations of
// k_bin_v REGRESSED via residency loss (VGPR/LDS growth). k_bin_v reverted
// byte-identical to r24 (130us). This round attacks the ~320us remainder:
//  * v<0>/v<1> decoupled (v<1> -> hacc2, summed in node_fv) -> ONE dispatch
//  * k_pad folded into fill_all's grid (one less launch boundary)
//  * CHK 4096->8192: halves scatter write amplification (2.6->5.2 edges/bin
//    runs) and halves returning cursor atomics.
#define CHK 8192
#define NCHG ((E_C2V + CHK - 1) / CHK)  // 196 (tail 2560)
#define NCHA ((E_A2V + CHK - 1) / CHK)  // 123 (tail 576)
#define PADB (((N_C + N_A) * 8 + 255) / 256)  // 1719
#define BINV 64
#define NBINV ((N_V + BINV - 1) / BINV)  // 1563 (last bin 32 nodes)
#define BINA 4
#define NBINA (N_A / BINA)  // 1250 exact
#define CAPG 1280  // mean 1024, sd 32 -> +8 sigma
#define CAPH 848   // mean 640,  sd 25 -> +8.3 sigma
#define CAPA 1040  // mean 800,  sd 28 -> +8.5 sigma
#define CURSTR 8   // pad cursors to one per 32B sector
#define CUR_TOT ((2 * NBINV + NBINA) * CURSTR)  // 35008 ints
#define CUR_BYTES (CUR_TOT * 4)                 // 140032 (64-aligned)

typedef float v2f __attribute__((ext_vector_type(2)));
typedef float f32x4 __attribute__((ext_vector_type(4)));
typedef short bf16x8 __attribute__((ext_vector_type(8)));
typedef unsigned long long u64;

// Pack (key_hi:17b, key_lo:16b, ea as bf16 RNE) into one u64.
__device__ __forceinline__ u64 pack_edge(int hi, int lo, float ea) {
  unsigned b = __float_as_uint(ea);
  b += 0x7FFFu + ((b >> 16) & 1u);  // round-to-nearest-even to bf16
  return ((u64)(unsigned)hi << 32) | ((u64)(unsigned)(lo & 0xFFFF) << 16) |
         (u64)(b >> 16);
}

__device__ __forceinline__ unsigned short bf16r(float x) {
  unsigned u = __float_as_uint(x);
  u += 0x7FFFu + ((u >> 16) & 1u);
  return (unsigned short)(u >> 16);
}

// Pack two floats to bf16 pair (RNE) in one uint: low=a, high=b.
__device__ __forceinline__ unsigned bf16pk(float a, float b) {
  unsigned ua = __float_as_uint(a);
  ua += 0x7FFFu + ((ua >> 16) & 1u);
  unsigned ub = __float_as_uint(b);
  ub += 0x7FFFu + ((ub >> 16) & 1u);
  return (ua >> 16) | (ub & 0xFFFF0000u);
}

// h2[j] (16 x float2 = 32 channels) += v * Wrow[2j..2j+1] via v_pk_fma_f32.
__device__ __forceinline__ void accrow2(v2f* __restrict__ h, float v,
                                        const float* __restrict__ Wrow) {
  const v2f* w = (const v2f*)Wrow;
  v2f vv = {v, v};
#pragma unroll
  for (int j = 0; j < 16; ++j) h[j] = __builtin_elementwise_fma(vv, w[j], h[j]);
}

__device__ __forceinline__ void relu2(v2f* __restrict__ h) {
  v2f z = {0.0f, 0.0f};
#pragma unroll
  for (int j = 0; j < 16; ++j) h[j] = __builtin_elementwise_max(h[j], z);
}

__device__ __forceinline__ void layer2(v2f* __restrict__ o2,
                                       const v2f* __restrict__ h,
                                       const float* __restrict__ W2,
                                       const float* __restrict__ b2) {
  const v2f* b = (const v2f*)b2;
#pragma unroll
  for (int j = 0; j < 16; ++j) o2[j] = b[j];
#pragma unroll
  for (int k = 0; k < EMB; ++k) {
    float hk = h[k >> 1][k & 1];
    accrow2(o2, hk, W2 + k * EMB);
  }
}

// -------- pack x_c / x_a rows to bf16[16] (32B rows, pad zero) --------
__device__ __forceinline__ void pad_body(int i, const float* __restrict__ x_c,
                                         const float* __restrict__ x_a,
                                         unsigned* __restrict__ xc_b,
                                         unsigned* __restrict__ xa_b) {
  if (i < N_C * 8) {
    int r = i >> 3, j = i & 7;
    xc_b[i] = (j < 7) ? bf16pk(x_c[r * D_C + 2 * j], x_c[r * D_C + 2 * j + 1])
                      : 0u;
  } else if (i < (N_C + N_A) * 8) {
    int k = i - N_C * 8;
    int r = k >> 3, j = k & 7;
    xa_b[k] = (j < 7) ? bf16pk(x_a[r * D_A + 2 * j], x_a[r * D_A + 2 * j + 1])
                      : 0u;
  }
}

__global__ __launch_bounds__(256) void k_pad(
    const float* __restrict__ x_c, const float* __restrict__ x_a,
    unsigned* __restrict__ xc_b, unsigned* __restrict__ xa_b) {
  pad_body(blockIdx.x * 256 + threadIdx.x, x_c, x_a, xc_b, xa_b);
}

// ======================= phase 1: fused count + fill =======================

__device__ __forceinline__ void bin_fill_g_body(
    int bid, int tid, const int* __restrict__ c2v_t,
    const int* __restrict__ c2v_s, const float* __restrict__ ea,
    int* __restrict__ gcur, u64* __restrict__ pay_g,
    unsigned* __restrict__ hist) {
  int e0 = bid * CHK;
  int n = E_C2V - e0;
  if (n > CHK) n = CHK;
  for (int i = tid; i < NBINV; i += 256) hist[i] = 0u;
  __syncthreads();
  const int4* t4 = (const int4*)(c2v_t + e0);
  for (int i = tid; i < (n >> 2); i += 256) {
    int4 v = t4[i];
    atomicAdd(&hist[v.x >> 6], 1u);
    atomicAdd(&hist[v.y >> 6], 1u);
    atomicAdd(&hist[v.z >> 6], 1u);
    atomicAdd(&hist[v.w >> 6], 1u);
  }
  __syncthreads();
  int rot = (bid * 131) % NBINV;
  for (int i = tid; i < NBINV; i += 256) {
    int ii = i + rot;
    if (ii >= NBINV) ii -= NBINV;
    unsigned c = hist[ii];
    hist[ii] =
        c ? (unsigned)(ii * CAPG + atomicAdd(&gcur[ii * CURSTR], (int)c)) : 0u;
  }
  __syncthreads();
  for (int i = tid; i < n; i += 256) {
    int e = e0 + i;
    int t = c2v_t[e];
    unsigned pos = atomicAdd(&hist[t >> 6], 1u);
    if (pos < (unsigned)(((t >> 6) + 1) * CAPG))  // 8-sigma overflow guard
      pay_g[pos] = pack_edge(t, c2v_s[e], ea[e]);
  }
}

__device__ __forceinline__ void bin_fill_ha_body(
    int bid, int tid, const int* __restrict__ a2v_t,
    const int* __restrict__ a2v_s, const float* __restrict__ ea,
    int* __restrict__ hcur, int* __restrict__ acur, u64* __restrict__ pay_h,
    u64* __restrict__ pay_a, unsigned* __restrict__ hist) {
  const int nb = NBINV + NBINA;
  int e0 = bid * CHK;
  int n = E_A2V - e0;
  if (n > CHK) n = CHK;
  for (int i = tid; i < nb; i += 256) hist[i] = 0u;
  __syncthreads();
  const int4* t4 = (const int4*)(a2v_t + e0);
  const int4* a4 = (const int4*)(a2v_s + e0);
  for (int i = tid; i < (n >> 2); i += 256) {
    int4 tv = t4[i];
    int4 av = a4[i];
    atomicAdd(&hist[tv.x >> 6], 1u);
    atomicAdd(&hist[tv.y >> 6], 1u);
    atomicAdd(&hist[tv.z >> 6], 1u);
    atomicAdd(&hist[tv.w >> 6], 1u);
    atomicAdd(&hist[NBINV + (av.x >> 2)], 1u);
    atomicAdd(&hist[NBINV + (av.y >> 2)], 1u);
    atomicAdd(&hist[NBINV + (av.z >> 2)], 1u);
    atomicAdd(&hist[NBINV + (av.w >> 2)], 1u);
  }
  __syncthreads();
  int rot = (bid * 131) % nb;
  for (int i = tid; i < nb; i += 256) {
    int ii = i + rot;
    if (ii >= nb) ii -= nb;
    unsigned c = hist[ii];
    unsigned base = 0u;
    if (c) {
      if (ii < NBINV)
        base = (unsigned)(ii * CAPH + atomicAdd(&hcur[ii * CURSTR], (int)c));
      else
        base = (unsigned)((ii - NBINV) * CAPA +
                          atomicAdd(&acur[(ii - NBINV) * CURSTR], (int)c));
    }
    hist[ii] = base;
  }
  __syncthreads();
  for (int i = tid; i < n; i += 256) {
    int e = e0 + i;
    int t = a2v_t[e];
    int a = a2v_s[e];
    u64 pk = pack_edge(t, a, ea[e]);
    unsigned ph = atomicAdd(&hist[t >> 6], 1u);
    if (ph < (unsigned)(((t >> 6) + 1) * CAPH)) pay_h[ph] = pk;
    unsigned pa = atomicAdd(&hist[NBINV + (a >> 2)], 1u);
    if (pa < (unsigned)(((a >> 2) + 1) * CAPA)) pay_a[pa] = pk;
  }
}

// big-ws path: fill g + fill ha + pad folded into one dispatch
__global__ __launch_bounds__(256) void k_fill_pad_all(
    const int* __restrict__ c2v_t, const int* __restrict__ c2v_s,
    const float* __restrict__ ea_g, const int* __restrict__ a2v_t,
    const int* __restrict__ a2v_s, const float* __restrict__ ea_ha,
    int* __restrict__ gcur, int* __restrict__ hcur, int* __restrict__ acur,
    u64* __restrict__ pay_g, u64* __restrict__ pay_h, u64* __restrict__ pay_a,
    const float* __restrict__ x_c, const float* __restrict__ x_a,
    unsigned* __restrict__ xc_b, unsigned* __restrict__ xa_b) {
  __shared__ unsigned hist[NBINV + NBINA];
  if (blockIdx.x < NCHG)
    bin_fill_g_body(blockIdx.x, threadIdx.x, c2v_t, c2v_s, ea_g, gcur, pay_g,
                    hist);
  else if (blockIdx.x < NCHG + NCHA)
    bin_fill_ha_body(blockIdx.x - NCHG, threadIdx.x, a2v_t, a2v_s, ea_ha, hcur,
                     acur, pay_h, pay_a, hist);
  else
    pad_body((int)(blockIdx.x - NCHG - NCHA) * 256 + threadIdx.x, x_c, x_a,
             xc_b, xa_b);
}

__global__ __launch_bounds__(256) void k_bin_fill_g(
    const int* __restrict__ c2v_t, const int* __restrict__ c2v_s,
    const float* __restrict__ ea_g, int* __restrict__ gcur,
    u64* __restrict__ pay_g) {
  __shared__ unsigned hist[NBINV + NBINA];
  bin_fill_g_body(blockIdx.x, threadIdx.x, c2v_t, c2v_s, ea_g, gcur, pay_g,
                  hist);
}

__global__ __launch_bounds__(256) void k_bin_fill_ha(
    const int* __restrict__ a2v_t, const int* __restrict__ a2v_s,
    const float* __restrict__ ea_ha, int* __restrict__ hcur,
    int* __restrict__ acur, u64* __restrict__ pay_h, u64* __restrict__ pay_a) {
  __shared__ unsigned hist[NBINV + NBINA];
  bin_fill_ha_body(blockIdx.x, threadIdx.x, a2v_t, a2v_s, ea_ha, hcur, acur,
                   pay_h, pay_a, hist);
}

// ======== phase 3: per-bin all-MFMA edge MLP + one-hot reduction ========
// Body byte-equivalent to r24's k_bin_v (130us config: 256t, 1 tile, 22KB
// LDS, VGPR 72), with plain-store epilogue (v<1> now writes hacc2).

__device__ __forceinline__ void bin_v_body(
    int b, int tid, const u64* __restrict__ pay, int CAP, int NSRC,
    const int* __restrict__ cur, const float* __restrict__ x_t,
    const unsigned* __restrict__ xs_b, const float* __restrict__ W1,
    const float* __restrict__ b1, const float* __restrict__ W2,
    const float* __restrict__ b2, const float* __restrict__ Wp,
    float* __restrict__ dst, unsigned short (*vals)[64][36], int (*nidl)[64],
    unsigned* degl, unsigned (*xtb)[7]) {
  int wv = tid >> 6, lane = tid & 63;
  int ne = cur[b * CURSTR];
  if (ne > CAP) ne = CAP;
  int nn = N_V - b * BINV;
  if (nn > BINV) nn = BINV;
  for (int i = tid; i < BINV + 1; i += 256) degl[i] = 0u;
  for (int i = tid; i < nn * 7; i += 256) {
    int node = i / 7, j = i - node * 7;
    const float* xr = x_t + (size_t)(b * BINV + node) * D_V;
    xtb[node][j] =
        (j < 6) ? bf16pk(xr[2 * j], xr[2 * j + 1]) : (unsigned)bf16r(xr[12]);
  }
  __syncthreads();
  int q = lane >> 4, n = lane & 15;
  // W1 fragments (feature order perm: k<13 -> row k; k==13 -> row 27 (ea);
  // 14<=k<28 -> row k-1; k>=28 -> 0)
  bf16x8 bW1[2];
#pragma unroll
  for (int ni = 0; ni < 2; ++ni)
#pragma unroll
    for (int j = 0; j < 8; ++j) {
      int k = q * 8 + j;
      int row = (k < 13) ? k : ((k == 13) ? 27 : k - 1);
      bW1[ni][j] =
          (k < 28) ? (short)bf16r(W1[row * EMB + ni * 16 + n]) : (short)0;
    }
  float bL1_0 = b1[n], bL1_1 = b1[16 + n];
  // W2 fragments
  bf16x8 bW2[2];
#pragma unroll
  for (int ni = 0; ni < 2; ++ni)
#pragma unroll
    for (int j = 0; j < 8; ++j)
      bW2[ni][j] = (short)bf16r(W2[(q * 8 + j) * EMB + ni * 16 + n]);
  float bL2_0 = b2[n], bL2_1 = b2[16 + n];
  const u64* payb = pay + (size_t)b * CAP;
  unsigned short* vw = &vals[wv][0][0];
  int* nw = &nidl[wv][0];
  f32x4 acc[4][2];
#pragma unroll
  for (int mi = 0; mi < 4; ++mi)
#pragma unroll
    for (int ni = 0; ni < 2; ++ni) acc[mi][ni] = (f32x4){0.f, 0.f, 0.f, 0.f};

  int idx0 = wv * 64 + lane;
  u64 p = payb[(idx0 < ne) ? idx0 : 0];
  if (idx0 >= ne) p = ~0ull;  // poison -> gate fails

  for (int base = wv * 64; base < ne; base += 256) {  // waves independent
    int idx = base + lane;
    // prefetch next round's payload (1 deep)
    int idxn = idx + 256;
    u64 pn = payb[(idxn < ne) ? idxn : 0];
    if (idxn >= ne) pn = ~0ull;
    // decode + gate
    int t = (int)(p >> 32);
    int s = (int)((p >> 16) & 0xFFFFull);
    unsigned eab = (unsigned)(p & 0xFFFFull);
    bool use = (((unsigned)t >> 6) == (unsigned)b) && (t < N_V) && (s < NSRC);
    int tl = t & (BINV - 1);
    nw[lane] = use ? tl : BINV;
    unsigned f0, f1, f2, f3, f4, f5, f6;
    uint4 xsa = {0u, 0u, 0u, 0u}, xsb2 = {0u, 0u, 0u, 0u};
    if (use) {
      const uint4* sp = (const uint4*)(xs_b + ((size_t)s << 3));
      xsa = sp[0];
      xsb2 = sp[1];
      f0 = xtb[tl][0];
      f1 = xtb[tl][1];
      f2 = xtb[tl][2];
      f3 = xtb[tl][3];
      f4 = xtb[tl][4];
      f5 = xtb[tl][5];
      f6 = xtb[tl][6] | (eab << 16);
      atomicAdd(&degl[tl], 1u);
    } else {
      f0 = f1 = f2 = f3 = f4 = f5 = f6 = 0u;
    }
    {  // stage feature row (8x ds_write_b64, 8B aligned)
      unsigned* hm = (unsigned*)vw + lane * 18;
      *(uint2*)(hm + 0) = make_uint2(f0, f1);
      *(uint2*)(hm + 2) = make_uint2(f2, f3);
      *(uint2*)(hm + 4) = make_uint2(f4, f5);
      *(uint2*)(hm + 6) = make_uint2(f6, xsa.x);
      *(uint2*)(hm + 8) = make_uint2(xsa.y, xsa.z);
      *(uint2*)(hm + 10) = make_uint2(xsa.w, xsb2.x);
      *(uint2*)(hm + 12) = make_uint2(xsb2.y, xsb2.z);
      *(uint2*)(hm + 14) = make_uint2(xsb2.w, 0u);
    }
    asm volatile("" ::: "memory");
    // ---- L1: read ALL feature frags, then MFMA + in-place h writeback ----
    union {
      u64 d[2];
      bf16x8 v;
    } af[4];
#pragma unroll
    for (int mi = 0; mi < 4; ++mi) {
      const u64* rp =
          (const u64*)((const char*)vw + (size_t)(mi * 16 + n) * 72 + q * 16);
      af[mi].d[0] = rp[0];
      af[mi].d[1] = rp[1];
    }
    asm volatile("" ::: "memory");
#pragma unroll
    for (int mi = 0; mi < 4; ++mi) {
#pragma unroll
      for (int ni = 0; ni < 2; ++ni) {
        float bb = ni ? bL1_1 : bL1_0;
        f32x4 c = {bb, bb, bb, bb};
        c = __builtin_amdgcn_mfma_f32_16x16x32_bf16(af[mi].v, bW1[ni], c, 0, 0,
                                                    0);
#pragma unroll
        for (int r = 0; r < 4; ++r)
          vw[(size_t)(mi * 16 + q * 4 + r) * 36 + ni * 16 + n] =
              (unsigned short)bf16r(fmaxf(c[r], 0.f));
      }
    }
    asm volatile("" ::: "memory");
    // ---- L2: read h frags, MFMA, transposed [ch][edge] writeback ----
    union {
      u64 d[2];
      bf16x8 v;
    } af2[4];
#pragma unroll
    for (int mi = 0; mi < 4; ++mi) {
      const u64* rp =
          (const u64*)((const char*)vw + (size_t)(mi * 16 + n) * 72 + q * 16);
      af2[mi].d[0] = rp[0];
      af2[mi].d[1] = rp[1];
    }
    asm volatile("" ::: "memory");
#pragma unroll
    for (int mi = 0; mi < 4; ++mi) {
#pragma unroll
      for (int ni = 0; ni < 2; ++ni) {
        float bb = ni ? bL2_1 : bL2_0;
        f32x4 c = {bb, bb, bb, bb};
        c = __builtin_amdgcn_mfma_f32_16x16x32_bf16(af2[mi].v, bW2[ni], c, 0,
                                                    0, 0);
        uint2 pk;
        pk.x = bf16pk(fmaxf(c[0], 0.f), fmaxf(c[1], 0.f));
        pk.y = bf16pk(fmaxf(c[2], 0.f), fmaxf(c[3], 0.f));
        *(uint2*)(vw + (size_t)(ni * 16 + n) * 72 + mi * 16 + q * 4) = pk;
      }
    }
    asm volatile("" ::: "memory");
    // ---- P3: one-hot MFMA reduction into register acc ----
#pragma unroll
    for (int kh = 0; kh < 2; ++kh) {
      int4 na = *(const int4*)(nw + kh * 32 + q * 8);
      int4 nb = *(const int4*)(nw + kh * 32 + q * 8 + 4);
      bf16x8 bf0 = *(const bf16x8*)(vw + n * 72 + kh * 32 + q * 8);
      bf16x8 bf1 = *(const bf16x8*)(vw + (16 + n) * 72 + kh * 32 + q * 8);
#pragma unroll
      for (int mi = 0; mi < 4; ++mi) {
        int mg = mi * 16 + n;
        union {
          unsigned u[4];
          bf16x8 v;
        } oh;
        oh.u[0] =
            ((na.x == mg) ? 0x3F80u : 0u) | ((na.y == mg) ? 0x3F800000u : 0u);
        oh.u[1] =
            ((na.z == mg) ? 0x3F80u : 0u) | ((na.w == mg) ? 0x3F800000u : 0u);
        oh.u[2] =
            ((nb.x == mg) ? 0x3F80u : 0u) | ((nb.y == mg) ? 0x3F800000u : 0u);
        oh.u[3] =
            ((nb.z == mg) ? 0x3F80u : 0u) | ((nb.w == mg) ? 0x3F800000u : 0u);
        acc[mi][0] = __builtin_amdgcn_mfma_f32_16x16x32_bf16(oh.v, bf0,
                                                             acc[mi][0], 0, 0,
                                                             0);
        acc[mi][1] = __builtin_amdgcn_mfma_f32_16x16x32_bf16(oh.v, bf1,
                                                             acc[mi][1], 0, 0,
                                                             0);
      }
    }
    asm volatile("" ::: "memory");
    p = pn;
  }
  __syncthreads();
  // merge: accf aliased onto (dead) staging LDS
  float* accf = (float*)&vals[0][0][0];  // 64*32 f32 = 8 KB
  for (int i = tid; i < BINV * EMB; i += 256) accf[i] = 0.f;
  __syncthreads();
#pragma unroll
  for (int mi = 0; mi < 4; ++mi)
#pragma unroll
    for (int ni = 0; ni < 2; ++ni)
#pragma unroll
      for (int r = 0; r < 4; ++r)
        atomicAdd(&accf[(mi * 16 + q * 4 + r) * EMB + ni * 16 + n],
                  acc[mi][ni][r]);
  __syncthreads();
  // mean + Wp projection + sole-owner writeback (plain store)
  int j = tid & 31;
  for (int node = tid >> 5; node < nn; node += 8) {
    float inv = 1.f / fmaxf((float)degl[node], 1.f);
    float out = 0.f;
#pragma unroll
    for (int k = 0; k < EMB; ++k)
      out = fmaf(accf[node * EMB + k], Wp[k * EMB + j], out);
    dst[(size_t)(b * BINV + node) * EMB + j] = out * inv;
  }
}

// merged g+h dispatch: block b < NBINV -> g-side into hacc; else h-side into
// hacc2 (independent buffers -> no ordering dependence).
__global__ __launch_bounds__(256) void k_bin_v2(
    const u64* __restrict__ pay_g, const int* __restrict__ gcur,
    const unsigned* __restrict__ xc_b, const float* __restrict__ gW1,
    const float* __restrict__ gb1, const float* __restrict__ gW2,
    const float* __restrict__ gb2, const float* __restrict__ gWp,
    float* __restrict__ hacc, const u64* __restrict__ pay_h,
    const int* __restrict__ hcur, const unsigned* __restrict__ xa_b,
    const float* __restrict__ hW1, const float* __restrict__ hb1,
    const float* __restrict__ hW2, const float* __restrict__ hb2,
    const float* __restrict__ hWp, float* __restrict__ hacc2,
    const float* __restrict__ x_v) {
  __shared__ __align__(16) unsigned short vals[4][64][36];  // 18432 B
  __shared__ __align__(16) int nidl[4][64];
  __shared__ unsigned degl[BINV + 1];
  __shared__ unsigned xtb[BINV][7];
  bool g = blockIdx.x < NBINV;
  int b = g ? blockIdx.x : (blockIdx.x - NBINV);
  bin_v_body(b, threadIdx.x, g ? pay_g : pay_h, g ? CAPG : CAPH,
             g ? N_C : N_A, g ? gcur : hcur, x_v, g ? xc_b : xa_b,
             g ? gW1 : hW1, g ? gb1 : hb1, g ? gW2 : hW2, g ? gb2 : hb2,
             g ? gWp : hWp, g ? hacc : hacc2, vals, nidl, degl, xtb);
}

// single-side wrapper (small-ws path)
__global__ __launch_bounds__(256) void k_bin_v1(
    const u64* __restrict__ pay, int CAP, int NSRC,
    const int* __restrict__ cur, const float* __restrict__ x_t,
    const unsigned* __restrict__ xs_b, const float* __restrict__ W1,
    const float* __restrict__ b1, const float* __restrict__ W2,
    const float* __restrict__ b2, const float* __restrict__ Wp,
    float* __restrict__ dst) {
  __shared__ __align__(16) unsigned short vals[4][64][36];
  __shared__ __align__(16) int nidl[4][64];
  __shared__ unsigned degl[BINV + 1];
  __shared__ unsigned xtb[BINV][7];
  bin_v_body(blockIdx.x, threadIdx.x, pay, CAP, NSRC, cur, x_t, xs_b, W1, b1,
             W2, b2, Wp, dst, vals, nidl, degl, xtb);
}

// a-side g_a MLP (FIN=47) per 4-node bin -> hacc_a (unchanged).
__global__ __launch_bounds__(256) void k_bin_a(
    const u64* __restrict__ pay, const int* __restrict__ cur,
    const float* __restrict__ xa, const float* __restrict__ fv,
    const float* __restrict__ W1, const float* __restrict__ b1,
    const float* __restrict__ W2, const float* __restrict__ b2,
    const float* __restrict__ Wp, float* __restrict__ hacc_a) {
  __shared__ __align__(16) unsigned short vals[4][64][36];
  __shared__ __align__(16) int nidl[4][64];
  __shared__ float accf_a[BINA * EMB];
  __shared__ unsigned degl[BINA + 1];
  __shared__ float xa_l[BINA * D_A];
  int tid = threadIdx.x;
  int wv = tid >> 6, lane = tid & 63;
  int b = blockIdx.x;
  int ne = cur[b * CURSTR];
  if (ne > CAPA) ne = CAPA;
  if (tid < BINA + 1) degl[tid] = 0u;
  if (tid < BINA * EMB) accf_a[tid] = 0.f;
  for (int i = tid; i < BINA * D_A; i += 256)
    xa_l[i] = xa[(size_t)b * (BINA * D_A) + i];
  __syncthreads();
  int q = lane >> 4, n = lane & 15;
  bf16x8 bfr[2];
#pragma unroll
  for (int ni = 0; ni < 2; ++ni)
#pragma unroll
    for (int j = 0; j < 8; ++j)
      bfr[ni][j] = (short)bf16r(W2[(q * 8 + j) * EMB + ni * 16 + n]);
  float bb0 = b2[n], bb1 = b2[16 + n];
  const u64* payb = pay + (size_t)b * CAPA;
  const v2f* b1v = (const v2f*)b1;
  unsigned short* vw = &vals[wv][0][0];
  int* nw = &nidl[wv][0];
  f32x4 acc2[2];
  acc2[0] = (f32x4){0.f, 0.f, 0.f, 0.f};
  acc2[1] = (f32x4){0.f, 0.f, 0.f, 0.f};

  for (int base = wv * 64; base < ne; base += 256) {
    int idx = base + lane;
    bool valid = idx < ne;
    int t = 0, a = 0;
    float eav = 0.f;
    if (valid) {
      u64 p = payb[idx];
      t = (int)(p >> 32);
      a = (int)((p >> 16) & 0xFFFFull);
      eav = __uint_as_float((unsigned)(p & 0xFFFFull) << 16);
    }
    bool use = valid && ((a >> 2) == b) && (t < N_V);
    nw[lane] = use ? (a & (BINA - 1)) : BINA;  // dummy row 4 discarded at merge
    v2f h[16];
    if (use) {
#pragma unroll
      for (int j = 0; j < 16; ++j) h[j] = b1v[j];
      const float* ps = xa_l + (a & (BINA - 1)) * D_A;
#pragma unroll
      for (int i = 0; i < D_A; ++i) accrow2(h, ps[i], W1 + i * EMB);
      const float4* pf = (const float4*)(fv + (size_t)t * EMB);
#pragma unroll
      for (int qq = 0; qq < 8; ++qq) {
        float4 f = pf[qq];
        accrow2(h, f.x, W1 + (D_A + 4 * qq) * EMB);
        accrow2(h, f.y, W1 + (D_A + 4 * qq + 1) * EMB);
        accrow2(h, f.z, W1 + (D_A + 4 * qq + 2) * EMB);
        accrow2(h, f.w, W1 + (D_A + 4 * qq + 3) * EMB);
      }
      accrow2(h, eav, W1 + 46 * EMB);
      relu2(h);
      atomicAdd(&degl[a & (BINA - 1)], 1u);
    } else {
      v2f z = {0.f, 0.f};
#pragma unroll
      for (int j = 0; j < 16; ++j) h[j] = z;
    }
    {
      unsigned* hm = (unsigned*)vw;
#pragma unroll
      for (int j = 0; j < 16; ++j) hm[lane * 18 + j] = bf16pk(h[j].x, h[j].y);
    }
    asm volatile("" ::: "memory");
    union {
      u64 d[2];
      bf16x8 v;
    } afr[4];
#pragma unroll
    for (int mi = 0; mi < 4; ++mi) {
      const u64* rp =
          (const u64*)((const char*)vw + (size_t)(mi * 16 + n) * 72 + q * 16);
      afr[mi].d[0] = rp[0];
      afr[mi].d[1] = rp[1];
    }
#pragma unroll
    for (int mi = 0; mi < 4; ++mi) {
#pragma unroll
      for (int ni = 0; ni < 2; ++ni) {
        f32x4 c = {0.f, 0.f, 0.f, 0.f};
        c = __builtin_amdgcn_mfma_f32_16x16x32_bf16(afr[mi].v, bfr[ni], c, 0,
                                                    0, 0);
        float bb = ni ? bb1 : bb0;
        uint2 pk;
        pk.x = bf16pk(fmaxf(c[0] + bb, 0.f), fmaxf(c[1] + bb, 0.f));
        pk.y = bf16pk(fmaxf(c[2] + bb, 0.f), fmaxf(c[3] + bb, 0.f));
        *(uint2*)(vw + (ni * 16 + n) * 72 + mi * 16 + q * 4) = pk;
      }
    }
    asm volatile("" ::: "memory");
#pragma unroll
    for (int kh = 0; kh < 2; ++kh) {
      int4 na = *(const int4*)(nw + kh * 32 + q * 8);
      int4 nb = *(const int4*)(nw + kh * 32 + q * 8 + 4);
      bf16x8 bf0 = *(const bf16x8*)(vw + n * 72 + kh * 32 + q * 8);
      bf16x8 bf1 = *(const bf16x8*)(vw + (16 + n) * 72 + kh * 32 + q * 8);
      int mg = n;  // single M-tile: nodes 0..3 live in rows 0..3
      union {
        unsigned u[4];
        bf16x8 v;
      } oh;
      oh.u[0] =
          ((na.x == mg) ? 0x3F80u : 0u) | ((na.y == mg) ? 0x3F800000u : 0u);
      oh.u[1] =
          ((na.z == mg) ? 0x3F80u : 0u) | ((na.w == mg) ? 0x3F800000u : 0u);
      oh.u[2] =
          ((nb.x == mg) ? 0x3F80u : 0u) | ((nb.y == mg) ? 0x3F800000u : 0u);
      oh.u[3] =
          ((nb.z == mg) ? 0x3F80u : 0u) | ((nb.w == mg) ? 0x3F800000u : 0u);
      acc2[0] = __builtin_amdgcn_mfma_f32_16x16x32_bf16(oh.v, bf0, acc2[0], 0,
                                                        0, 0);
      acc2[1] = __builtin_amdgcn_mfma_f32_16x16x32_bf16(oh.v, bf1, acc2[1], 0,
                                                        0, 0);
    }
    asm volatile("" ::: "memory");
  }
  __syncthreads();
  if (q == 0) {  // rows 0..3 (node = r); dummy row 4 lives at q=1 -> dropped
#pragma unroll
    for (int ni = 0; ni < 2; ++ni)
#pragma unroll
      for (int r = 0; r < 4; ++r)
        atomicAdd(&accf_a[r * EMB + ni * 16 + n], acc2[ni][r]);
  }
  __syncthreads();
  int node = tid >> 5;
  int j = tid & 31;
  if (node < BINA) {
    float inv = 1.f / fmaxf((float)degl[node], 1.f);
    float out = 0.f;
#pragma unroll
    for (int k = 0; k < EMB; ++k)
      out = fmaf(accf_a[node * EMB + k], Wp[k * EMB + j], out);
    hacc_a[(size_t)(b * BINA + node) * EMB + j] = out * inv;
  }
}

// -------- f_v node MLP: h = fb1 + hacc + hacc2, IN-PLACE on hacc --------
__global__ __launch_bounds__(256) void k_node_fv(
    const float* __restrict__ xv_g, float* hf, const float* __restrict__ hf2,
    const float* __restrict__ fW1, const float* __restrict__ fb1,
    const float* __restrict__ fW2, const float* __restrict__ fb2) {
  int v = blockIdx.x * blockDim.x + threadIdx.x;
  if (v >= N_V) return;
  v2f* row = (v2f*)(hf + (size_t)v * EMB);
  const v2f* row2 = (const v2f*)(hf2 + (size_t)v * EMB);
  const v2f* bv = (const v2f*)fb1;
  v2f h[16];
#pragma unroll
  for (int j = 0; j < 16; ++j) h[j] = bv[j] + row[j] + row2[j];
  const float* pv = xv_g + (size_t)v * D_V;
#pragma unroll
  for (int i = 0; i < D_V; ++i) accrow2(h, pv[i], fW1 + i * EMB);
  relu2(h);
  v2f o2[16];
  layer2(o2, h, fW2, fb2);
  v2f z = {0.0f, 0.0f};
#pragma unroll
  for (int j = 0; j < 16; ++j)
    row[j] = __builtin_elementwise_max(o2[j], z);  // relu_out (+idempotent)
}

// -------- f_a node MLP on pre-accumulated hidden -> d_out ------
__global__ __launch_bounds__(256) void k_node_fa(
    const float* __restrict__ xa, const float* __restrict__ hacc_a,
    const float* __restrict__ W1, const float* __restrict__ b1,
    const float* __restrict__ W2, const float* __restrict__ b2,
    float* __restrict__ out) {
  int a = blockIdx.x * blockDim.x + threadIdx.x;
  if (a >= N_A) return;
  const v2f* hr = (const v2f*)(hacc_a + (size_t)a * EMB);
  const v2f* bv = (const v2f*)b1;
  v2f h[16];
#pragma unroll
  for (int j = 0; j < 16; ++j) h[j] = bv[j] + hr[j];
  const float2* pa = (const float2*)(xa + (size_t)a * D_A);
#pragma unroll
  for (int i = 0; i < 7; ++i) {
    float2 w = pa[i];
    accrow2(h, w.x, W1 + (2 * i) * EMB);
    accrow2(h, w.y, W1 + (2 * i + 1) * EMB);
  }
  relu2(h);
  v2f o2[16];
  layer2(o2, h, W2, b2);
  v2f z = {0.0f, 0.0f};
  v2f* dst = (v2f*)(out + (size_t)a * EMB);
#pragma unroll
  for (int j = 0; j < 16; ++j)
    dst[j] = __builtin_elementwise_max(o2[j], z);
}

extern "C" void kernel_launch(void* const* d_in, const int* in_sizes, int n_in,
                              void* d_out, int out_size, void* d_ws,
                              size_t ws_size, hipStream_t stream) {
  const float* x_c = (const float*)d_in[0];
  const float* x_v = (const float*)d_in[1];
  const float* x_a = (const float*)d_in[2];
  const int* c2v_s = (const int*)d_in[3];
  const int* c2v_t = (const int*)d_in[4];
  const int* a2v_s = (const int*)d_in[5];
  const int* a2v_t = (const int*)d_in[6];
  const float* ea_c2v = (const float*)d_in[7];
  const float* ea_a2v = (const float*)d_in[8];
  const float* gv_W1 = (const float*)d_in[9];
  const float* gv_b1 = (const float*)d_in[10];
  const float* gv_W2 = (const float*)d_in[11];
  const float* gv_b2 = (const float*)d_in[12];
  const float* hv_W1 = (const float*)d_in[13];
  const float* hv_b1 = (const float*)d_in[14];
  const float* hv_W2 = (const float*)d_in[15];
  const float* hv_b2 = (const float*)d_in[16];
  const float* fv_W1 = (const float*)d_in[17];
  const float* fv_b1 = (const float*)d_in[18];
  const float* fv_W2 = (const float*)d_in[19];
  const float* fv_b2 = (const float*)d_in[20];
  const float* ga_W1 = (const float*)d_in[21];
  const float* ga_b1 = (const float*)d_in[22];
  const float* ga_W2 = (const float*)d_in[23];
  const float* ga_b2 = (const float*)d_in[24];
  const float* fa_W1 = (const float*)d_in[25];
  const float* fa_b1 = (const float*)d_in[26];
  const float* fa_W2 = (const float*)d_in[27];
  const float* fa_b2 = (const float*)d_in[28];

  // ---- workspace layout ----
  char* w = (char*)d_ws;
  int* cur = (int*)w;  // [0, CUR_BYTES)
  int* gcur = cur;
  int* hcur = gcur + NBINV * CURSTR;
  int* acur = hcur + NBINV * CURSTR;
  size_t off = CUR_BYTES;
  unsigned* xc_b = (unsigned*)(w + off);
  off += (size_t)N_C * 8 * 4;
  unsigned* xa_b = (unsigned*)(w + off);
  off += (size_t)N_A * 8 * 4;
  float* hacc = (float*)(w + off);  // N_V*32 (becomes fv in-place)
  off += (size_t)N_V * EMB * 4;
  float* hacc2 = (float*)(w + off);  // N_V*32 (h-side partial)
  off += (size_t)N_V * EMB * 4;
  float* hacc_a = (float*)(w + off);  // N_A*32
  off += (size_t)N_A * EMB * 4;
  u64* pay = (u64*)(w + off);

  const size_t pay_big =
      ((size_t)NBINV * (CAPG + CAPH) + (size_t)NBINA * CAPA) * 8;
  bool big = ws_size >= off + pay_big;

  u64* pay_g = pay;
  u64* pay_h = big ? (pay + (size_t)NBINV * CAPG) : pay;  // small: reuse g
  u64* pay_a = pay_h + (size_t)NBINV * CAPH;

  // only the cursors need zeroing (hacc/hacc2/hacc_a fully written)
  hipMemsetAsync(d_ws, 0, (size_t)CUR_BYTES, stream);

  if (big) {
    k_fill_pad_all<<<NCHG + NCHA + PADB, 256, 0, stream>>>(
        c2v_t, c2v_s, ea_c2v, a2v_t, a2v_s, ea_a2v, gcur, hcur, acur, pay_g,
        pay_h, pay_a, x_c, x_a, xc_b, xa_b);
    k_bin_v2<<<2 * NBINV, 256, 0, stream>>>(
        pay_g, gcur, xc_b, gv_W1, gv_b1, gv_W2, gv_b2,
        fv_W1 + (size_t)D_V * EMB, hacc, pay_h, hcur, xa_b, hv_W1, hv_b1,
        hv_W2, hv_b2, fv_W1 + (size_t)(D_V + EMB) * EMB, hacc2, x_v);
  } else {
    // small-ws: pay_g region time-multiplexed with pay_h/pay_a
    k_pad<<<PADB, 256, 0, stream>>>(x_c, x_a, xc_b, xa_b);
    k_bin_fill_g<<<NCHG, 256, 0, stream>>>(c2v_t, c2v_s, ea_c2v, gcur, pay_g);
    k_bin_v1<<<NBINV, 256, 0, stream>>>(
        pay_g, CAPG, N_C, gcur, x_v, xc_b, gv_W1, gv_b1, gv_W2, gv_b2,
        fv_W1 + (size_t)D_V * EMB, hacc);
    k_bin_fill_ha<<<NCHA, 256, 0, stream>>>(a2v_t, a2v_s, ea_a2v, hcur, acur,
                                            pay_h, pay_a);
    k_bin_v1<<<NBINV, 256, 0, stream>>>(
        pay_h, CAPH, N_A, hcur, x_v, xa_b, hv_W1, hv_b1, hv_W2, hv_b2,
        fv_W1 + (size_t)(D_V + EMB) * EMB, hacc2);
  }
  // f_v in-place: hacc rows (g) + hacc2 rows (h) -> fv rows in hacc
  k_node_fv<<<(N_V + 255) / 256, 256, 0, stream>>>(
      x_v, hacc, hacc2, fv_W1, fv_b1, fv_W2, fv_b2);
  // a-side g_a MLP + one-hot MFMA reduce -> hacc_a
  k_bin_a<<<NBINA, 256, 0, stream>>>(pay_a, acur, x_a, hacc, ga_W1, ga_b1,
                                     ga_W2, ga_b2,
                                     fa_W1 + (size_t)D_A * EMB, hacc_a);
  // f_a -> out
  k_node_fa<<<(N_A + 255) / 256, 256, 0, stream>>>(
      x_a, hacc_a, fa_W1, fa_b1, fa_W2, fa_b2, (float*)d_out);
}